// Round 6
// baseline (422.977 us; speedup 1.0000x reference)
//
#include <hip/hip_runtime.h>
#include <hip/hip_bf16.h>
#include <stdint.h>
#include <stddef.h>

#define DIMV 2048
#define CTXV 512
#define BV   8192
#define NPV  512
#define NSV  256

typedef __attribute__((ext_vector_type(8))) __bf16 bf16x8;
typedef __attribute__((ext_vector_type(4))) __bf16 bf16x4;
typedef __attribute__((ext_vector_type(4))) float f32x4;

__device__ __forceinline__ void gload_lds16(const void* g, void* l) {
    __builtin_amdgcn_global_load_lds(
        (const __attribute__((address_space(1))) unsigned int*)g,
        (__attribute__((address_space(3))) unsigned int*)l,
        16, 0, 0);
}

// ---------------------------------------------------------------------------
// Batched fp32 -> bf16 convert (x, ctx, 9 weights)
// ---------------------------------------------------------------------------
struct CvtArgs {
    const float* src[11];
    __bf16*      dst[11];
};

__global__ __launch_bounds__(256) void cvt_all(CvtArgs a) {
    constexpr int NSEG = 11;
    constexpr unsigned cum[NSEG + 1] = {
        0u, 2097152u, 2621440u, 2752512u, 2883584u, 3014656u,
        3080192u, 3145728u, 3153920u, 3284992u, 3416064u, 3481600u};
    const unsigned total = cum[NSEG];
    for (unsigned c = blockIdx.x * blockDim.x + threadIdx.x; c < total;
         c += gridDim.x * blockDim.x) {
        const float* sp = a.src[0];
        __bf16*      dp = a.dst[0];
        unsigned     base = 0;
#pragma unroll
        for (int t = 1; t < NSEG; ++t) {
            const bool g = (c >= cum[t]);
            sp   = g ? a.src[t] : sp;
            dp   = g ? a.dst[t] : dp;
            base = g ? cum[t] : base;
        }
        const unsigned off = (c - base) * 8u;
        f32x4 v0 = *(const f32x4*)(sp + off);
        f32x4 v1 = *(const f32x4*)(sp + off + 4);
        bf16x8 o;
#pragma unroll
        for (int e = 0; e < 4; ++e) { o[e] = (__bf16)v0[e]; o[e + 4] = (__bf16)v1[e]; }
        *(bf16x8*)(dp + off) = o;
    }
}

// ---------------------------------------------------------------------------
// Transpose-convert Wpred (2048x512 f32, row-major) -> WpredT (512x2048 bf16)
// 64x64 tiles through padded LDS. Grid 256 blocks x 256 threads.
// ---------------------------------------------------------------------------
__global__ __launch_bounds__(256)
void cvtT_wpred(const float* __restrict__ W, __bf16* __restrict__ WT) {
    __shared__ float t[64 * 65];
    const int bi  = blockIdx.x & 31;   // row-block over 2048
    const int bj  = blockIdx.x >> 5;   // col-block over 512
    const int tid = threadIdx.x;
    const int tr  = tid >> 4;
    const int tc  = tid & 15;
#pragma unroll
    for (int rr = 0; rr < 4; ++rr) {
        const int r = tr + rr * 16;
        f32x4 v = *(const f32x4*)(W + (size_t)(bi * 64 + r) * 512 + bj * 64 + tc * 4);
#pragma unroll
        for (int e = 0; e < 4; ++e) t[(tc * 4 + e) * 65 + r] = v[e];
    }
    __syncthreads();
#pragma unroll
    for (int rr = 0; rr < 4; ++rr) {
        const int c = tr + rr * 16;
        bf16x4 o;
#pragma unroll
        for (int e = 0; e < 4; ++e) o[e] = (__bf16)t[c * 65 + tc * 4 + e];
        *(bf16x4*)(WT + (size_t)(bj * 64 + c) * 2048 + bi * 64 + tc * 4) = o;
    }
}

// ---------------------------------------------------------------------------
// biascomb[0:512)  = Wpv2 @ b_pred ;  biascomb[512:768) = Wvip @ b_pred
// One wave per output row (2048-dot). Grid 96 x 512.
// ---------------------------------------------------------------------------
__global__ __launch_bounds__(512)
void bias_comb(const __bf16* __restrict__ Wpv2, const __bf16* __restrict__ Wvip,
               const float* __restrict__ b, float* __restrict__ out) {
    const int tid  = threadIdx.x;
    const int gw   = blockIdx.x * 8 + (tid >> 6);   // 0..767
    const int lane = tid & 63;
    const __bf16* row = (gw < 512) ? (Wpv2 + (size_t)gw * 2048)
                                   : (Wvip + (size_t)(gw - 512) * 2048);
    float acc = 0.f;
#pragma unroll
    for (int c = 0; c < 4; ++c) {
        const int j = lane * 32 + c * 8;
        bf16x8 w = *(const bf16x8*)(row + j);
        f32x4 b0 = *(const f32x4*)(b + j);
        f32x4 b1 = *(const f32x4*)(b + j + 4);
#pragma unroll
        for (int e = 0; e < 4; ++e) acc += (float)w[e] * b0[e];
#pragma unroll
        for (int e = 0; e < 4; ++e) acc += (float)w[e + 4] * b1[e];
    }
#pragma unroll
    for (int off = 32; off > 0; off >>= 1) acc += __shfl_down(acc, off);
    if (lane == 0) out[gw] = acc;
}

// ---------------------------------------------------------------------------
// 256x256 tile, BK=32, 8 waves (2x4, per-wave 128x64), 512 thr, 16x16x32 MFMA,
// 2-phase dbuf LDS (64 KB total). Staging global_load_lds(16B); read-side XOR
// swizzle (chunk ^= (row>>1)&3) via pre-swizzled GLOBAL source (rounds 2-5,
// measured 0 conflicts). MFMA operands SWAPPED:
//   batch row = m0 + wr*128 + i*16 + (lane&15)
//   out col   = n0 + wc*64 + j*16 + (lane>>4)*4 + r     [harness-verified]
// Panel order: bx = wg / ntN (consecutive blocks share the A-panel; whole W
// stays L2-resident). XCD-bijective swizzle (all grids %8==0).
// ---------------------------------------------------------------------------
struct GemmDesc {
    const __bf16* A0; int ldA0;
    const __bf16* W1; const __bf16* W2; int ldW;
    int NB1;             // N-concat boundary (mult of 256; huge if none)
    int N1cols, N2cols;  // row strides of out1/out2
    int K, ntN;
    int epi;             // 0 bias->bf16, 1 relu-region, 2 subr, 3 plain, 4 bias768+relu-region
    const float* bias;
    const __bf16* subp;
    void* out1; void* out2;
};

#define GEOM8                                                     \
    const int tid  = threadIdx.x;                                 \
    const int wave = tid >> 6;                                    \
    const int lane = tid & 63;                                    \
    const int lhi  = lane >> 4;                                   \
    const int llo  = lane & 15;                                   \
    const int wr   = wave >> 2;                                   \
    const int wc   = wave & 3;                                    \
    const int rins = lane >> 2;                                   \
    const int ch   = lane & 3;

#define LOAD_FRAGS4(BUF, af, bfr)                                     \
    _Pragma("unroll")                                                 \
    for (int i = 0; i < 8; ++i) {                                     \
        const int r  = wr * 128 + i * 16 + llo;                       \
        const int pc = lhi ^ ((r >> 1) & 3);                          \
        af[i] = *(const bf16x8*)(ldsA[BUF] + r * 64 + pc * 16);       \
    }                                                                 \
    _Pragma("unroll")                                                 \
    for (int j = 0; j < 4; ++j) {                                     \
        const int r  = wc * 64 + j * 16 + llo;                        \
        const int pc = lhi ^ ((r >> 1) & 3);                          \
        bfr[j] = *(const bf16x8*)(ldsB[BUF] + r * 64 + pc * 16);      \
    }

#define MFMA_ALL4(af, bfr, acc)                                                       \
    _Pragma("unroll")                                                                 \
    for (int i = 0; i < 8; ++i)                                                       \
        _Pragma("unroll")                                                             \
        for (int j = 0; j < 4; ++j)                                                   \
            acc[i][j] = __builtin_amdgcn_mfma_f32_16x16x32_bf16(bfr[j], af[i], acc[i][j], 0, 0, 0);

__global__ __launch_bounds__(512, 2)
void pe_gemm4(GemmDesc dA_, GemmDesc dB_, GemmDesc dC_, int s1, int s2)
{
    __shared__ __align__(16) char ldsA[2][16384];
    __shared__ __align__(16) char ldsB[2][16384];

    const int nwg = gridDim.x;
    const int bid = blockIdx.x;
    int wg = (bid & 7) * (nwg >> 3) + (bid >> 3);
    GemmDesc d = dA_;
    if (wg >= s2)      { d = dC_; wg -= s2; }
    else if (wg >= s1) { d = dB_; wg -= s1; }
    if (d.out1 == nullptr) return;

    const int bx = wg / d.ntN;          // A-panel-major: neighbors share bx
    const int by = wg - bx * d.ntN;
    const int m0 = bx * 256;
    const int n0 = by * 256;

    const bool reg2  = (n0 >= d.NB1);
    const __bf16* Wc = reg2 ? d.W2 : d.W1;
    const int n0r    = reg2 ? (n0 - d.NB1) : n0;

    GEOM8

    const f32x4 fzero = {0.f, 0.f, 0.f, 0.f};
    f32x4 acc[8][4];
#pragma unroll
    for (int i = 0; i < 8; ++i)
#pragma unroll
        for (int j = 0; j < 4; ++j) acc[i][j] = fzero;

    const int nsteps = d.K >> 5;

#define STAGE4(S, BUF)                                                        \
    {                                                                         \
        const int kb_ = (S) * 32;                                             \
        _Pragma("unroll")                                                     \
        for (int h = 0; h < 2; ++h) {                                         \
            const int q   = wave + h * 8;                                     \
            const int row = q * 16 + rins;                                    \
            const int kc  = ch ^ ((row >> 1) & 3);                            \
            const int kk  = kb_ + kc * 8;                                     \
            gload_lds16(d.A0 + (size_t)(m0 + row) * d.ldA0 + kk,              \
                        ldsA[BUF] + q * 1024);                                \
            gload_lds16(Wc + (size_t)(n0r + row) * d.ldW + kk,                \
                        ldsB[BUF] + q * 1024);                                \
        }                                                                     \
    }

    STAGE4(0, 0)
    __syncthreads();
    int cur = 0;
    for (int s = 0; s < nsteps; ++s) {
        if (s + 1 < nsteps) STAGE4(s + 1, cur ^ 1)
        bf16x8 af[8], bfr[4];
        LOAD_FRAGS4(cur, af, bfr)
        MFMA_ALL4(af, bfr, acc)
        __syncthreads();
        cur ^= 1;
    }
#undef STAGE4

#pragma unroll
    for (int i = 0; i < 8; ++i) {
#pragma unroll
        for (int j = 0; j < 4; ++j) {
            const int rowg = m0 + wr * 128 + i * 16 + llo;
            const int colb = wc * 64 + j * 16 + lhi * 4;
            if (d.epi == 0) {            // BIAS (fp32 vec) -> bf16
                const size_t idx = (size_t)rowg * d.N1cols + (n0 + colb);
                f32x4 b4 = *(const f32x4*)(d.bias + n0 + colb);
                bf16x4 o;
#pragma unroll
                for (int r = 0; r < 4; ++r) o[r] = (__bf16)(acc[i][j][r] + b4[r]);
                *(bf16x4*)((__bf16*)d.out1 + idx) = o;
            } else if (d.epi == 1) {     // RELU -> bf16, N-region
                __bf16* op    = reg2 ? (__bf16*)d.out2 : (__bf16*)d.out1;
                const int ldo = reg2 ? d.N2cols : d.N1cols;
                const size_t idx = (size_t)rowg * ldo + (n0r + colb);
                bf16x4 o;
#pragma unroll
                for (int r = 0; r < 4; ++r) o[r] = (__bf16)fmaxf(acc[i][j][r], 0.f);
                *(bf16x4*)(op + idx) = o;
            } else if (d.epi == 2) {     // SUBR: relu(subp - acc) -> bf16
                const size_t idx = (size_t)rowg * d.N1cols + (n0 + colb);
                bf16x4 s4 = *(const bf16x4*)(d.subp + idx);
                bf16x4 o;
#pragma unroll
                for (int r = 0; r < 4; ++r)
                    o[r] = (__bf16)fmaxf((float)s4[r] - acc[i][j][r], 0.f);
                *(bf16x4*)((__bf16*)d.out1 + idx) = o;
            } else if (d.epi == 3) {     // plain -> bf16 (Wcomb)
                const size_t idx = (size_t)rowg * d.N1cols + (n0 + colb);
                bf16x4 o;
#pragma unroll
                for (int r = 0; r < 4; ++r) o[r] = (__bf16)acc[i][j][r];
                *(bf16x4*)((__bf16*)d.out1 + idx) = o;
            } else {                     // bias768 + RELU -> bf16, N-region
                __bf16* op    = reg2 ? (__bf16*)d.out2 : (__bf16*)d.out1;
                const int ldo = reg2 ? d.N2cols : d.N1cols;
                const size_t idx = (size_t)rowg * ldo + (n0r + colb);
                f32x4 b4 = *(const f32x4*)(d.bias + n0 + colb);
                bf16x4 o;
#pragma unroll
                for (int r = 0; r < 4; ++r)
                    o[r] = (__bf16)fmaxf(acc[i][j][r] + b4[r], 0.f);
                *(bf16x4*)(op + idx) = o;
            }
        }
    }
}

// ---------------------------------------------------------------------------
// Merged FILT (steps 7+8), 256x256 tiles, sequential pos -> neg (acc reused):
//   out_pos = 0.9*r_pos + 0.1*relu( (x-pred) - rpv2 @ Wpepos^T)
//   out_neg = 0.9*r_neg + 0.1*relu( (pred-x) - rpv1 @ Wpeneg^T - rsom @ Wsomd^T)
// First neg prefetch issued BEFORE the pos epilogue (HBM latency hides there).
// ---------------------------------------------------------------------------
__global__ __launch_bounds__(512, 2)
void pe_filt4(const __bf16* __restrict__ rpv2, const __bf16* __restrict__ Wpepos,
              const __bf16* __restrict__ rpv1, const __bf16* __restrict__ rsom,
              const __bf16* __restrict__ Wpeneg, const __bf16* __restrict__ Wsomd,
              const __bf16* __restrict__ xbf, const __bf16* __restrict__ predb,
              const float* __restrict__ rpos, const float* __restrict__ rneg,
              float* __restrict__ outp, float* __restrict__ outn)
{
    __shared__ __align__(16) char ldsA[2][16384];
    __shared__ __align__(16) char ldsB[2][16384];

    const int nwg = gridDim.x;
    const int bid = blockIdx.x;
    const int wg  = (bid & 7) * (nwg >> 3) + (bid >> 3);
    const int bx  = wg >> 3;         // A-panel-major (ntN = 8)
    const int by  = wg & 7;
    const int m0  = bx * 256;
    const int n0  = by * 256;

    GEOM8

#define STAGE_F(Asrc, ldA, Wsrc, ldW, KB, BUF)                                \
    {                                                                         \
        _Pragma("unroll")                                                     \
        for (int h = 0; h < 2; ++h) {                                         \
            const int q   = wave + h * 8;                                     \
            const int row = q * 16 + rins;                                    \
            const int kc  = ch ^ ((row >> 1) & 3);                            \
            const int kk  = (KB) + kc * 8;                                    \
            gload_lds16((Asrc) + (size_t)(m0 + row) * (ldA) + kk,             \
                        ldsA[BUF] + q * 1024);                                \
            gload_lds16((Wsrc) + (size_t)(n0 + row) * (ldW) + kk,             \
                        ldsB[BUF] + q * 1024);                                \
        }                                                                     \
    }

    const f32x4 fzero = {0.f, 0.f, 0.f, 0.f};
    f32x4 acc[8][4];
#pragma unroll
    for (int i = 0; i < 8; ++i)
#pragma unroll
        for (int j = 0; j < 4; ++j) acc[i][j] = fzero;

    // ---- POS K-loop (K=512, 16 steps) ----
    STAGE_F(rpv2, NPV, Wpepos, NPV, 0, 0)
    __syncthreads();
    int cur = 0;
    for (int s = 0; s < 16; ++s) {
        if (s + 1 < 16) STAGE_F(rpv2, NPV, Wpepos, NPV, (s + 1) * 32, cur ^ 1)
        bf16x8 af[8], bfr[4];
        LOAD_FRAGS4(cur, af, bfr)
        MFMA_ALL4(af, bfr, acc)
        __syncthreads();
        cur ^= 1;
    }
    // cur == 0; both buffers free. Prefetch first NEG tile before epilogue.
    STAGE_F(rpv1, NPV, Wpeneg, NPV, 0, cur)

    // ---- POS epilogue ----
#pragma unroll
    for (int i = 0; i < 8; ++i) {
#pragma unroll
        for (int j = 0; j < 4; ++j) {
            const int rowg = m0 + wr * 128 + i * 16 + llo;
            const int colg = n0 + wc * 64 + j * 16 + lhi * 4;
            const size_t idx = (size_t)rowg * 2048 + colg;
            f32x4 rp  = *(const f32x4*)(rpos + idx);
            bf16x4 xb = *(const bf16x4*)(xbf + idx);
            bf16x4 pb = *(const bf16x4*)(predb + idx);
            f32x4 o;
#pragma unroll
            for (int r = 0; r < 4; ++r) {
                const float dd = (float)xb[r] - (float)pb[r];
                o[r] = 0.9f * rp[r] + 0.1f * fmaxf(dd - acc[i][j][r], 0.f);
            }
            *(f32x4*)(outp + idx) = o;
        }
    }
    __syncthreads();   // drains prefetch; all waves past pos phase

    // ---- NEG K-loop (K=768 = 512 rpv1/Wpeneg + 256 rsom/Wsomd, 24 steps) ----
#pragma unroll
    for (int i = 0; i < 8; ++i)
#pragma unroll
        for (int j = 0; j < 4; ++j) acc[i][j] = fzero;

    for (int s = 0; s < 24; ++s) {
        if (s + 1 < 24) {
            const int k0n = (s + 1) * 32;
            if (k0n < 512) {
                STAGE_F(rpv1, NPV, Wpeneg, NPV, k0n, cur ^ 1)
            } else {
                STAGE_F(rsom, NSV, Wsomd, NSV, k0n - 512, cur ^ 1)
            }
        }
        bf16x8 af[8], bfr[4];
        LOAD_FRAGS4(cur, af, bfr)
        MFMA_ALL4(af, bfr, acc)
        __syncthreads();
        cur ^= 1;
    }

    // ---- NEG epilogue ----
#pragma unroll
    for (int i = 0; i < 8; ++i) {
#pragma unroll
        for (int j = 0; j < 4; ++j) {
            const int rowg = m0 + wr * 128 + i * 16 + llo;
            const int colg = n0 + wc * 64 + j * 16 + lhi * 4;
            const size_t idx = (size_t)rowg * 2048 + colg;
            f32x4 rn  = *(const f32x4*)(rneg + idx);
            bf16x4 xb = *(const bf16x4*)(xbf + idx);
            bf16x4 pb = *(const bf16x4*)(predb + idx);
            f32x4 o;
#pragma unroll
            for (int r = 0; r < 4; ++r) {
                const float dd = (float)pb[r] - (float)xb[r];
                o[r] = 0.9f * rn[r] + 0.1f * fmaxf(dd - acc[i][j][r], 0.f);
            }
            *(f32x4*)(outn + idx) = o;
        }
    }
#undef STAGE_F
}

extern "C" void kernel_launch(void* const* d_in, const int* in_sizes, int n_in,
                              void* d_out, int out_size, void* d_ws, size_t ws_size,
                              hipStream_t stream) {
    (void)in_sizes; (void)n_in; (void)out_size; (void)ws_size;

    const float* x       = (const float*)d_in[0];
    const float* ctx     = (const float*)d_in[1];
    const float* r_pos   = (const float*)d_in[2];
    const float* r_neg   = (const float*)d_in[3];
    const float* Wpred   = (const float*)d_in[4];
    const float* bpred   = (const float*)d_in[5];
    const float* Wpv1    = (const float*)d_in[6];
    const float* Wpv2    = (const float*)d_in[7];
    const float* Wvip    = (const float*)d_in[8];
    const float* Wsomin  = (const float*)d_in[9];
    const float* Wvipsom = (const float*)d_in[10];
    const float* Wpepos  = (const float*)d_in[11];
    const float* Wpeneg  = (const float*)d_in[12];
    const float* Wsomd   = (const float*)d_in[13];

    char* ws = (char*)d_ws;
    __bf16* x_bf      = (__bf16*)ws; ws += (size_t)BV * DIMV * 2;
    __bf16* ctx_bf    = (__bf16*)ws; ws += (size_t)BV * CTXV * 2;
    __bf16* pred_bf   = (__bf16*)ws; ws += (size_t)BV * DIMV * 2;
    __bf16* rpv1_bf   = (__bf16*)ws; ws += (size_t)BV * NPV * 2;
    __bf16* rpv2_bf   = (__bf16*)ws; ws += (size_t)BV * NPV * 2;
    __bf16* rvip_bf   = (__bf16*)ws; ws += (size_t)BV * NSV * 2;
    __bf16* ssom_bf   = (__bf16*)ws; ws += (size_t)BV * NSV * 2;
    __bf16* rsom_bf   = (__bf16*)ws; ws += (size_t)BV * NSV * 2;
    __bf16* Wpred_bf  = (__bf16*)ws; ws += (size_t)DIMV * CTXV * 2;
    __bf16* Wpv1_bf   = (__bf16*)ws; ws += (size_t)NPV * DIMV * 2;
    __bf16* Wpv2_bf   = (__bf16*)ws; ws += (size_t)NPV * DIMV * 2;
    __bf16* Wvip_bf   = (__bf16*)ws; ws += (size_t)NSV * DIMV * 2;
    __bf16* Wsomin_bf = (__bf16*)ws; ws += (size_t)NSV * DIMV * 2;
    __bf16* Wvipsom_bf= (__bf16*)ws; ws += (size_t)NSV * NSV * 2;
    __bf16* Wpepos_bf = (__bf16*)ws; ws += (size_t)DIMV * NPV * 2;
    __bf16* Wpeneg_bf = (__bf16*)ws; ws += (size_t)DIMV * NPV * 2;
    __bf16* Wsomd_bf  = (__bf16*)ws; ws += (size_t)DIMV * NSV * 2;
    __bf16* WpredT_bf = (__bf16*)ws; ws += (size_t)CTXV * DIMV * 2;
    __bf16* Wcomb2    = (__bf16*)ws; ws += (size_t)NPV * CTXV * 2;
    __bf16* Wcombv    = (__bf16*)ws; ws += (size_t)NSV * CTXV * 2;
    float*  biascomb  = (float*)ws;  ws += 768 * 4;

    float* out_pos = (float*)d_out;
    float* out_neg = out_pos + (size_t)BV * DIMV;

    CvtArgs ca;
    ca.src[0] = x;       ca.dst[0] = x_bf;
    ca.src[1] = ctx;     ca.dst[1] = ctx_bf;
    ca.src[2] = Wpred;   ca.dst[2] = Wpred_bf;
    ca.src[3] = Wpv1;    ca.dst[3] = Wpv1_bf;
    ca.src[4] = Wpv2;    ca.dst[4] = Wpv2_bf;
    ca.src[5] = Wvip;    ca.dst[5] = Wvip_bf;
    ca.src[6] = Wsomin;  ca.dst[6] = Wsomin_bf;
    ca.src[7] = Wvipsom; ca.dst[7] = Wvipsom_bf;
    ca.src[8] = Wpepos;  ca.dst[8] = Wpepos_bf;
    ca.src[9] = Wpeneg;  ca.dst[9] = Wpeneg_bf;
    ca.src[10] = Wsomd;  ca.dst[10] = Wsomd_bf;
    cvt_all<<<dim3(2048), dim3(256), 0, stream>>>(ca);
    cvtT_wpred<<<dim3(256), dim3(256), 0, stream>>>(Wpred, WpredT_bf);
    bias_comb<<<dim3(96), dim3(512), 0, stream>>>(Wpv2_bf, Wvip_bf, bpred, biascomb);

    const int BIG = 1 << 28;
    GemmDesc dz;
    dz.A0 = nullptr; dz.ldA0 = 0; dz.W1 = dz.W2 = nullptr; dz.ldW = 0;
    dz.NB1 = BIG; dz.N1cols = dz.N2cols = 0; dz.K = 32; dz.ntN = 1;
    dz.epi = 3; dz.bias = nullptr; dz.subp = nullptr;
    dz.out1 = dz.out2 = nullptr;

    // Wcomb2 = Wpv2 @ Wpred (512x512), Wcombv = Wvip @ Wpred (256x512)
    GemmDesc d_c2 = dz;
    d_c2.A0 = Wpv2_bf; d_c2.ldA0 = DIMV;
    d_c2.W1 = d_c2.W2 = WpredT_bf; d_c2.ldW = DIMV;
    d_c2.K = DIMV; d_c2.ntN = 2; d_c2.N1cols = CTXV; d_c2.epi = 3;
    d_c2.out1 = Wcomb2;

    GemmDesc d_cv = d_c2;
    d_cv.A0 = Wvip_bf;
    d_cv.out1 = Wcombv;

    pe_gemm4<<<dim3(8), dim3(512), 0, stream>>>(d_c2, d_cv, dz, 4, 6);

    // BIG3: pred (256 blocks) || 2+3 (96) || 4'+5' (96)
    GemmDesc d_pred = dz;
    d_pred.A0 = ctx_bf; d_pred.ldA0 = CTXV;
    d_pred.W1 = d_pred.W2 = Wpred_bf; d_pred.ldW = CTXV;
    d_pred.K = CTXV; d_pred.ntN = 8; d_pred.N1cols = DIMV; d_pred.epi = 0;
    d_pred.bias = bpred; d_pred.out1 = pred_bf;

    GemmDesc d_23 = dz;
    d_23.A0 = x_bf; d_23.ldA0 = DIMV;
    d_23.W1 = Wpv1_bf; d_23.W2 = Wsomin_bf; d_23.ldW = DIMV;
    d_23.K = DIMV; d_23.ntN = 3; d_23.NB1 = NPV;
    d_23.N1cols = NPV; d_23.N2cols = NSV; d_23.epi = 1;
    d_23.out1 = rpv1_bf; d_23.out2 = ssom_bf;

    GemmDesc d_45 = dz;
    d_45.A0 = ctx_bf; d_45.ldA0 = CTXV;
    d_45.W1 = Wcomb2; d_45.W2 = Wcombv; d_45.ldW = CTXV;
    d_45.K = CTXV; d_45.ntN = 3; d_45.NB1 = NPV;
    d_45.N1cols = NPV; d_45.N2cols = NSV; d_45.epi = 4;
    d_45.bias = biascomb; d_45.out1 = rpv2_bf; d_45.out2 = rvip_bf;

    pe_gemm4<<<dim3(448), dim3(512), 0, stream>>>(d_pred, d_23, d_45, 256, 352);

    // rsom = relu(ssom - rvip @ Wvipsom^T)   (32 blocks)
    GemmDesc d_som = dz;
    d_som.A0 = rvip_bf; d_som.ldA0 = NSV;
    d_som.W1 = d_som.W2 = Wvipsom_bf; d_som.ldW = NSV;
    d_som.K = NSV; d_som.ntN = 1; d_som.N1cols = NSV; d_som.epi = 2;
    d_som.subp = ssom_bf; d_som.out1 = rsom_bf;

    pe_gemm4<<<dim3(32), dim3(512), 0, stream>>>(d_som, d_som, d_som, 32, 64);

    // merged FILT (256 blocks)
    pe_filt4<<<dim3(256), dim3(512), 0, stream>>>(
        rpv2_bf, Wpepos_bf, rpv1_bf, rsom_bf, Wpeneg_bf, Wsomd_bf,
        x_bf, pred_bf, r_pos, r_neg, out_pos, out_neg);
}

// Round 7
// 313.688 us; speedup vs baseline: 1.3484x; 1.3484x over previous
//
#include <hip/hip_runtime.h>
#include <hip/hip_bf16.h>
#include <stdint.h>
#include <stddef.h>

#define DIMV 2048
#define CTXV 512
#define BV   8192
#define NPV  512
#define NSV  256

typedef __attribute__((ext_vector_type(8))) __bf16 bf16x8;
typedef __attribute__((ext_vector_type(4))) __bf16 bf16x4;
typedef __attribute__((ext_vector_type(4))) float f32x4;

__device__ __forceinline__ void gload_lds16(const void* g, void* l) {
    __builtin_amdgcn_global_load_lds(
        (const __attribute__((address_space(1))) unsigned int*)g,
        (__attribute__((address_space(3))) unsigned int*)l,
        16, 0, 0);
}

#define WAIT_VM8  asm volatile("s_waitcnt vmcnt(8)" ::: "memory")
#define WAIT_VM4  asm volatile("s_waitcnt vmcnt(4)" ::: "memory")
#define WAIT_VM0  asm volatile("s_waitcnt vmcnt(0)" ::: "memory")
#define WAIT_LGKM asm volatile("s_waitcnt lgkmcnt(0)" ::: "memory")
#define SBAR      __builtin_amdgcn_s_barrier()
#define SCHEDB    __builtin_amdgcn_sched_barrier(0)

// ---------------------------------------------------------------------------
// Batched fp32 -> bf16 convert (x, ctx, 9 weights)
// ---------------------------------------------------------------------------
struct CvtArgs {
    const float* src[11];
    __bf16*      dst[11];
};

__global__ __launch_bounds__(256) void cvt_all(CvtArgs a) {
    constexpr int NSEG = 11;
    constexpr unsigned cum[NSEG + 1] = {
        0u, 2097152u, 2621440u, 2752512u, 2883584u, 3014656u,
        3080192u, 3145728u, 3153920u, 3284992u, 3416064u, 3481600u};
    const unsigned total = cum[NSEG];
    for (unsigned c = blockIdx.x * blockDim.x + threadIdx.x; c < total;
         c += gridDim.x * blockDim.x) {
        const float* sp = a.src[0];
        __bf16*      dp = a.dst[0];
        unsigned     base = 0;
#pragma unroll
        for (int t = 1; t < NSEG; ++t) {
            const bool g = (c >= cum[t]);
            sp   = g ? a.src[t] : sp;
            dp   = g ? a.dst[t] : dp;
            base = g ? cum[t] : base;
        }
        const unsigned off = (c - base) * 8u;
        f32x4 v0 = *(const f32x4*)(sp + off);
        f32x4 v1 = *(const f32x4*)(sp + off + 4);
        bf16x8 o;
#pragma unroll
        for (int e = 0; e < 4; ++e) { o[e] = (__bf16)v0[e]; o[e + 4] = (__bf16)v1[e]; }
        *(bf16x8*)(dp + off) = o;
    }
}

// ---------------------------------------------------------------------------
// Transpose-convert Wpred (2048x512 f32) -> WpredT (512x2048 bf16)
// ---------------------------------------------------------------------------
__global__ __launch_bounds__(256)
void cvtT_wpred(const float* __restrict__ W, __bf16* __restrict__ WT) {
    __shared__ float t[64 * 65];
    const int bi  = blockIdx.x & 31;
    const int bj  = blockIdx.x >> 5;
    const int tid = threadIdx.x;
    const int tr  = tid >> 4;
    const int tc  = tid & 15;
#pragma unroll
    for (int rr = 0; rr < 4; ++rr) {
        const int r = tr + rr * 16;
        f32x4 v = *(const f32x4*)(W + (size_t)(bi * 64 + r) * 512 + bj * 64 + tc * 4);
#pragma unroll
        for (int e = 0; e < 4; ++e) t[(tc * 4 + e) * 65 + r] = v[e];
    }
    __syncthreads();
#pragma unroll
    for (int rr = 0; rr < 4; ++rr) {
        const int c = tr + rr * 16;
        bf16x4 o;
#pragma unroll
        for (int e = 0; e < 4; ++e) o[e] = (__bf16)t[c * 65 + tc * 4 + e];
        *(bf16x4*)(WT + (size_t)(bj * 64 + c) * 2048 + bi * 64 + tc * 4) = o;
    }
}

// ---------------------------------------------------------------------------
// biascomb[0:512) = Wpv2 @ b_pred ; biascomb[512:768) = Wvip @ b_pred
// ---------------------------------------------------------------------------
__global__ __launch_bounds__(512)
void bias_comb(const __bf16* __restrict__ Wpv2, const __bf16* __restrict__ Wvip,
               const float* __restrict__ b, float* __restrict__ out) {
    const int tid  = threadIdx.x;
    const int gw   = blockIdx.x * 8 + (tid >> 6);
    const int lane = tid & 63;
    const __bf16* row = (gw < 512) ? (Wpv2 + (size_t)gw * 2048)
                                   : (Wvip + (size_t)(gw - 512) * 2048);
    float acc = 0.f;
#pragma unroll
    for (int c = 0; c < 4; ++c) {
        const int j = lane * 32 + c * 8;
        bf16x8 w = *(const bf16x8*)(row + j);
        f32x4 b0 = *(const f32x4*)(b + j);
        f32x4 b1 = *(const f32x4*)(b + j + 4);
#pragma unroll
        for (int e = 0; e < 4; ++e) acc += (float)w[e] * b0[e];
#pragma unroll
        for (int e = 0; e < 4; ++e) acc += (float)w[e + 4] * b1[e];
    }
#pragma unroll
    for (int off = 32; off > 0; off >>= 1) acc += __shfl_down(acc, off);
    if (lane == 0) out[gw] = acc;
}

// ---------------------------------------------------------------------------
// 128x128 tile, BK=32, 4 waves (2x2 of 64x64), 256 thr, 16x16x32 MFMA.
// 3-BUFFER COUNTED-vmcnt PIPELINE (T3/T4-minimum):
//   prologue: STAGE(0,b0); STAGE(1,b1);
//   iter s:   STAGE(s+2, (s+2)%3); s_waitcnt vmcnt(8); s_barrier;
//             ds_read frags(buf s%3); setprio(1); 16 MFMA; setprio(0);
//             s_waitcnt lgkmcnt(0); sched_barrier; s_barrier;
// vmcnt(8) = 2 stages x 4 loads/thread in flight -> waits only for stage s.
// Buf (s+2)%3 == (s-1)%3: last read at iter s-1, protected by its end barrier.
// Staging: global_load_lds(16B); read-side XOR swizzle (chunk ^= (row>>1)&3)
// via pre-swizzled GLOBAL source (rounds 2-6, 0 conflicts measured).
// MFMA operands SWAPPED:
//   batch row = m0 + wr*64 + i*16 + (lane&15)
//   out col   = n0 + wc*64 + j*16 + (lane>>4)*4 + r     [harness-verified]
// ---------------------------------------------------------------------------
struct GemmDesc {
    const __bf16* A; int ldA;
    const __bf16* W1; const __bf16* W2; int ldW;
    int NB1;             // N-concat boundary (mult of 128; huge if none)
    int N1cols, N2cols;
    int K, ntN;
    int epi;             // 0 bias->bf16, 1 relu-region, 2 subr, 3 plain, 4 bias768+relu-region
    const float* bias;
    const __bf16* subp;
    void* out1; void* out2;
};

#define GEOM4                                                     \
    const int tid  = threadIdx.x;                                 \
    const int wave = tid >> 6;                                    \
    const int lane = tid & 63;                                    \
    const int lhi  = lane >> 4;                                   \
    const int llo  = lane & 15;                                   \
    const int wr   = wave >> 1;                                   \
    const int wc   = wave & 1;                                    \
    const int rins = lane >> 2;                                   \
    const int ch   = lane & 3;

#define LOAD_FRAGS5(BUF, af, bfr)                                     \
    _Pragma("unroll")                                                 \
    for (int i = 0; i < 4; ++i) {                                     \
        const int r  = wr * 64 + i * 16 + llo;                        \
        const int pc = lhi ^ ((r >> 1) & 3);                          \
        af[i] = *(const bf16x8*)(&ldsA[BUF][r * 64 + pc * 16]);       \
    }                                                                 \
    _Pragma("unroll")                                                 \
    for (int j = 0; j < 4; ++j) {                                     \
        const int r  = wc * 64 + j * 16 + llo;                        \
        const int pc = lhi ^ ((r >> 1) & 3);                          \
        bfr[j] = *(const bf16x8*)(&ldsB[BUF][r * 64 + pc * 16]);      \
    }

#define MFMA16(af, bfr, acc)                                                          \
    __builtin_amdgcn_s_setprio(1);                                                    \
    _Pragma("unroll")                                                                 \
    for (int i = 0; i < 4; ++i)                                                       \
        _Pragma("unroll")                                                             \
        for (int j = 0; j < 4; ++j)                                                   \
            acc[i][j] = __builtin_amdgcn_mfma_f32_16x16x32_bf16(bfr[j], af[i], acc[i][j], 0, 0, 0); \
    __builtin_amdgcn_s_setprio(0);

__global__ __launch_bounds__(256, 3)
void pe_gemm5(GemmDesc dA_, GemmDesc dB_, GemmDesc dC_, int s1, int s2)
{
    __shared__ __align__(16) char ldsA[3][8192];
    __shared__ __align__(16) char ldsB[3][8192];

    const int nwg = gridDim.x;
    const int bid = blockIdx.x;
    int wg = (bid & 7) * (nwg >> 3) + (bid >> 3);   // XCD-bijective (nwg%8==0)
    GemmDesc d = dA_;
    if (wg >= s2)      { d = dC_; wg -= s2; }
    else if (wg >= s1) { d = dB_; wg -= s1; }

    const int bx = wg / d.ntN;          // A-panel-major
    const int by = wg - bx * d.ntN;
    const int m0 = bx * 128;
    const int n0 = by * 128;

    const bool reg2  = (n0 >= d.NB1);
    const __bf16* Wc = reg2 ? d.W2 : d.W1;
    const int n0r    = reg2 ? (n0 - d.NB1) : n0;

    GEOM4

    const f32x4 fzero = {0.f, 0.f, 0.f, 0.f};
    f32x4 acc[4][4];
#pragma unroll
    for (int i = 0; i < 4; ++i)
#pragma unroll
        for (int j = 0; j < 4; ++j) acc[i][j] = fzero;

    const int nsteps = d.K >> 5;

#define STAGE5(S, BUF)                                                        \
    {                                                                         \
        const int kb_ = (S) * 32;                                             \
        _Pragma("unroll")                                                     \
        for (int half = 0; half < 2; ++half) {                                \
            const int rt = wave * 32 + half * 16 + rins;                      \
            const int kc = ch ^ ((rt >> 1) & 3);                              \
            const int kk = kb_ + kc * 8;                                      \
            gload_lds16(d.A + (size_t)(m0 + rt) * d.ldA + kk,                 \
                        &ldsA[BUF][wave * 2048 + half * 1024]);               \
            gload_lds16(Wc + (size_t)(n0r + rt) * d.ldW + kk,                 \
                        &ldsB[BUF][wave * 2048 + half * 1024]);               \
        }                                                                     \
    }

    STAGE5(0, 0)
    if (nsteps > 1) STAGE5(1, 1)
    for (int s = 0; s < nsteps; ++s) {
        if (s + 2 < nsteps) { STAGE5(s + 2, (s + 2) % 3) WAIT_VM8; }
        else if (s + 1 < nsteps) { WAIT_VM4; }
        else { WAIT_VM0; }
        SBAR;
        const int cb = s % 3;
        bf16x8 af[4], bfr[4];
        LOAD_FRAGS5(cb, af, bfr)
        MFMA16(af, bfr, acc)
        WAIT_LGKM; SCHEDB;
        SBAR;
    }
#undef STAGE5

#pragma unroll
    for (int i = 0; i < 4; ++i) {
#pragma unroll
        for (int j = 0; j < 4; ++j) {
            const int rowg = m0 + wr * 64 + i * 16 + llo;
            const int colb = wc * 64 + j * 16 + lhi * 4;
            if (d.epi == 0) {            // BIAS -> bf16
                const size_t idx = (size_t)rowg * d.N1cols + (n0 + colb);
                f32x4 b4 = *(const f32x4*)(d.bias + n0 + colb);
                bf16x4 o;
#pragma unroll
                for (int r = 0; r < 4; ++r) o[r] = (__bf16)(acc[i][j][r] + b4[r]);
                *(bf16x4*)((__bf16*)d.out1 + idx) = o;
            } else if (d.epi == 1) {     // RELU -> bf16, N-region
                __bf16* op    = reg2 ? (__bf16*)d.out2 : (__bf16*)d.out1;
                const int ldo = reg2 ? d.N2cols : d.N1cols;
                const size_t idx = (size_t)rowg * ldo + (n0r + colb);
                bf16x4 o;
#pragma unroll
                for (int r = 0; r < 4; ++r) o[r] = (__bf16)fmaxf(acc[i][j][r], 0.f);
                *(bf16x4*)(op + idx) = o;
            } else if (d.epi == 2) {     // SUBR: relu(subp - acc) -> bf16
                const size_t idx = (size_t)rowg * d.N1cols + (n0 + colb);
                bf16x4 s4 = *(const bf16x4*)(d.subp + idx);
                bf16x4 o;
#pragma unroll
                for (int r = 0; r < 4; ++r)
                    o[r] = (__bf16)fmaxf((float)s4[r] - acc[i][j][r], 0.f);
                *(bf16x4*)((__bf16*)d.out1 + idx) = o;
            } else if (d.epi == 3) {     // plain -> bf16
                const size_t idx = (size_t)rowg * d.N1cols + (n0 + colb);
                bf16x4 o;
#pragma unroll
                for (int r = 0; r < 4; ++r) o[r] = (__bf16)acc[i][j][r];
                *(bf16x4*)((__bf16*)d.out1 + idx) = o;
            } else {                     // bias768 + RELU -> bf16, N-region
                __bf16* op    = reg2 ? (__bf16*)d.out2 : (__bf16*)d.out1;
                const int ldo = reg2 ? d.N2cols : d.N1cols;
                const size_t idx = (size_t)rowg * ldo + (n0r + colb);
                f32x4 b4 = *(const f32x4*)(d.bias + n0 + colb);
                bf16x4 o;
#pragma unroll
                for (int r = 0; r < 4; ++r)
                    o[r] = (__bf16)fmaxf(acc[i][j][r] + b4[r], 0.f);
                *(bf16x4*)(op + idx) = o;
            }
        }
    }
}

// ---------------------------------------------------------------------------
// Merged FILT (steps 7+8), 128x128 tiles, same 3-buffer counted pipeline.
//   out_pos = 0.9*r_pos + 0.1*relu( (x-pred) - rpv2 @ Wpepos^T)
//   out_neg = 0.9*r_neg + 0.1*relu( (pred-x) - rpv1 @ Wpeneg^T - rsom @ Wsomd^T)
// NEG prologue stages issued BEFORE the POS epilogue (latency hides there).
// ---------------------------------------------------------------------------
__global__ __launch_bounds__(256, 3)
void pe_filt5(const __bf16* __restrict__ rpv2, const __bf16* __restrict__ Wpepos,
              const __bf16* __restrict__ rpv1, const __bf16* __restrict__ rsom,
              const __bf16* __restrict__ Wpeneg, const __bf16* __restrict__ Wsomd,
              const __bf16* __restrict__ xbf, const __bf16* __restrict__ predb,
              const float* __restrict__ rpos, const float* __restrict__ rneg,
              float* __restrict__ outp, float* __restrict__ outn)
{
    __shared__ __align__(16) char ldsA[3][8192];
    __shared__ __align__(16) char ldsB[3][8192];

    const int nwg = gridDim.x;
    const int bid = blockIdx.x;
    const int wg  = (bid & 7) * (nwg >> 3) + (bid >> 3);
    const int bx  = wg >> 4;          // A-panel-major, 16 n-tiles
    const int by  = wg & 15;
    const int m0  = bx * 128;
    const int n0  = by * 128;

    GEOM4

#define STAGE_F(Asrc, ldAv, Wsrc, ldWv, KB, BUF)                              \
    {                                                                         \
        _Pragma("unroll")                                                     \
        for (int half = 0; half < 2; ++half) {                                \
            const int rt = wave * 32 + half * 16 + rins;                      \
            const int kc = ch ^ ((rt >> 1) & 3);                              \
            const int kk = (KB) + kc * 8;                                     \
            gload_lds16((Asrc) + (size_t)(m0 + rt) * (ldAv) + kk,             \
                        &ldsA[BUF][wave * 2048 + half * 1024]);               \
            gload_lds16((Wsrc) + (size_t)(n0 + rt) * (ldWv) + kk,             \
                        &ldsB[BUF][wave * 2048 + half * 1024]);               \
        }                                                                     \
    }
#define STAGE_NEG(S, BUF)                                                     \
    {                                                                         \
        if ((S) < 16) { STAGE_F(rpv1, NPV, Wpeneg, NPV, (S) * 32, BUF) }      \
        else          { STAGE_F(rsom, NSV, Wsomd, NSV, ((S) - 16) * 32, BUF) }\
    }

    const f32x4 fzero = {0.f, 0.f, 0.f, 0.f};
    f32x4 acc[4][4];
#pragma unroll
    for (int i = 0; i < 4; ++i)
#pragma unroll
        for (int j = 0; j < 4; ++j) acc[i][j] = fzero;

    // ---- POS K-loop (K=512, 16 steps) ----
    STAGE_F(rpv2, NPV, Wpepos, NPV, 0, 0)
    STAGE_F(rpv2, NPV, Wpepos, NPV, 32, 1)
    for (int s = 0; s < 16; ++s) {
        if (s + 2 < 16) { STAGE_F(rpv2, NPV, Wpepos, NPV, (s + 2) * 32, (s + 2) % 3) WAIT_VM8; }
        else if (s + 1 < 16) { WAIT_VM4; }
        else { WAIT_VM0; }
        SBAR;
        const int cb = s % 3;
        bf16x8 af[4], bfr[4];
        LOAD_FRAGS5(cb, af, bfr)
        MFMA16(af, bfr, acc)
        WAIT_LGKM; SCHEDB;
        SBAR;
    }
    // buffers all free. Issue NEG prologue before the POS epilogue.
    STAGE_NEG(0, 0)
    STAGE_NEG(1, 1)

    // ---- POS epilogue ----
#pragma unroll
    for (int i = 0; i < 4; ++i) {
#pragma unroll
        for (int j = 0; j < 4; ++j) {
            const int rowg = m0 + wr * 64 + i * 16 + llo;
            const int colg = n0 + wc * 64 + j * 16 + lhi * 4;
            const size_t idx = (size_t)rowg * 2048 + colg;
            f32x4 rp  = *(const f32x4*)(rpos + idx);
            bf16x4 xb = *(const bf16x4*)(xbf + idx);
            bf16x4 pb = *(const bf16x4*)(predb + idx);
            f32x4 o;
#pragma unroll
            for (int r = 0; r < 4; ++r) {
                const float dd = (float)xb[r] - (float)pb[r];
                o[r] = 0.9f * rp[r] + 0.1f * fmaxf(dd - acc[i][j][r], 0.f);
            }
            *(f32x4*)(outp + idx) = o;
            acc[i][j] = fzero;
        }
    }

    // ---- NEG K-loop (K=768 = 512 rpv1/Wpeneg + 256 rsom/Wsomd, 24 steps) ----
    for (int s = 0; s < 24; ++s) {
        if (s + 2 < 24) { STAGE_NEG(s + 2, (s + 2) % 3) WAIT_VM8; }
        else if (s + 1 < 24) { WAIT_VM4; }
        else { WAIT_VM0; }
        SBAR;
        const int cb = s % 3;
        bf16x8 af[4], bfr[4];
        LOAD_FRAGS5(cb, af, bfr)
        MFMA16(af, bfr, acc)
        WAIT_LGKM; SCHEDB;
        SBAR;
    }

    // ---- NEG epilogue ----
#pragma unroll
    for (int i = 0; i < 4; ++i) {
#pragma unroll
        for (int j = 0; j < 4; ++j) {
            const int rowg = m0 + wr * 64 + i * 16 + llo;
            const int colg = n0 + wc * 64 + j * 16 + lhi * 4;
            const size_t idx = (size_t)rowg * 2048 + colg;
            f32x4 rn  = *(const f32x4*)(rneg + idx);
            bf16x4 xb = *(const bf16x4*)(xbf + idx);
            bf16x4 pb = *(const bf16x4*)(predb + idx);
            f32x4 o;
#pragma unroll
            for (int r = 0; r < 4; ++r) {
                const float dd = (float)pb[r] - (float)xb[r];
                o[r] = 0.9f * rn[r] + 0.1f * fmaxf(dd - acc[i][j][r], 0.f);
            }
            *(f32x4*)(outn + idx) = o;
        }
    }
#undef STAGE_NEG
#undef STAGE_F
}

extern "C" void kernel_launch(void* const* d_in, const int* in_sizes, int n_in,
                              void* d_out, int out_size, void* d_ws, size_t ws_size,
                              hipStream_t stream) {
    (void)in_sizes; (void)n_in; (void)out_size; (void)ws_size;

    const float* x       = (const float*)d_in[0];
    const float* ctx     = (const float*)d_in[1];
    const float* r_pos   = (const float*)d_in[2];
    const float* r_neg   = (const float*)d_in[3];
    const float* Wpred   = (const float*)d_in[4];
    const float* bpred   = (const float*)d_in[5];
    const float* Wpv1    = (const float*)d_in[6];
    const float* Wpv2    = (const float*)d_in[7];
    const float* Wvip    = (const float*)d_in[8];
    const float* Wsomin  = (const float*)d_in[9];
    const float* Wvipsom = (const float*)d_in[10];
    const float* Wpepos  = (const float*)d_in[11];
    const float* Wpeneg  = (const float*)d_in[12];
    const float* Wsomd   = (const float*)d_in[13];

    char* ws = (char*)d_ws;
    __bf16* x_bf      = (__bf16*)ws; ws += (size_t)BV * DIMV * 2;
    __bf16* ctx_bf    = (__bf16*)ws; ws += (size_t)BV * CTXV * 2;
    __bf16* pred_bf   = (__bf16*)ws; ws += (size_t)BV * DIMV * 2;
    __bf16* rpv1_bf   = (__bf16*)ws; ws += (size_t)BV * NPV * 2;
    __bf16* rpv2_bf   = (__bf16*)ws; ws += (size_t)BV * NPV * 2;
    __bf16* rvip_bf   = (__bf16*)ws; ws += (size_t)BV * NSV * 2;
    __bf16* ssom_bf   = (__bf16*)ws; ws += (size_t)BV * NSV * 2;
    __bf16* rsom_bf   = (__bf16*)ws; ws += (size_t)BV * NSV * 2;
    __bf16* Wpred_bf  = (__bf16*)ws; ws += (size_t)DIMV * CTXV * 2;
    __bf16* Wpv1_bf   = (__bf16*)ws; ws += (size_t)NPV * DIMV * 2;
    __bf16* Wpv2_bf   = (__bf16*)ws; ws += (size_t)NPV * DIMV * 2;
    __bf16* Wvip_bf   = (__bf16*)ws; ws += (size_t)NSV * DIMV * 2;
    __bf16* Wsomin_bf = (__bf16*)ws; ws += (size_t)NSV * DIMV * 2;
    __bf16* Wvipsom_bf= (__bf16*)ws; ws += (size_t)NSV * NSV * 2;
    __bf16* Wpepos_bf = (__bf16*)ws; ws += (size_t)DIMV * NPV * 2;
    __bf16* Wpeneg_bf = (__bf16*)ws; ws += (size_t)DIMV * NPV * 2;
    __bf16* Wsomd_bf  = (__bf16*)ws; ws += (size_t)DIMV * NSV * 2;
    __bf16* WpredT_bf = (__bf16*)ws; ws += (size_t)CTXV * DIMV * 2;
    __bf16* Wcomb2    = (__bf16*)ws; ws += (size_t)NPV * CTXV * 2;
    __bf16* Wcombv    = (__bf16*)ws; ws += (size_t)NSV * CTXV * 2;
    float*  biascomb  = (float*)ws;  ws += 768 * 4;

    float* out_pos = (float*)d_out;
    float* out_neg = out_pos + (size_t)BV * DIMV;

    CvtArgs ca;
    ca.src[0] = x;       ca.dst[0] = x_bf;
    ca.src[1] = ctx;     ca.dst[1] = ctx_bf;
    ca.src[2] = Wpred;   ca.dst[2] = Wpred_bf;
    ca.src[3] = Wpv1;    ca.dst[3] = Wpv1_bf;
    ca.src[4] = Wpv2;    ca.dst[4] = Wpv2_bf;
    ca.src[5] = Wvip;    ca.dst[5] = Wvip_bf;
    ca.src[6] = Wsomin;  ca.dst[6] = Wsomin_bf;
    ca.src[7] = Wvipsom; ca.dst[7] = Wvipsom_bf;
    ca.src[8] = Wpepos;  ca.dst[8] = Wpepos_bf;
    ca.src[9] = Wpeneg;  ca.dst[9] = Wpeneg_bf;
    ca.src[10] = Wsomd;  ca.dst[10] = Wsomd_bf;
    cvt_all<<<dim3(2048), dim3(256), 0, stream>>>(ca);
    cvtT_wpred<<<dim3(256), dim3(256), 0, stream>>>(Wpred, WpredT_bf);
    bias_comb<<<dim3(96), dim3(512), 0, stream>>>(Wpv2_bf, Wvip_bf, bpred, biascomb);

    const int BIG = 1 << 28;
    GemmDesc dz;
    dz.A = nullptr; dz.ldA = 0; dz.W1 = dz.W2 = nullptr; dz.ldW = 0;
    dz.NB1 = BIG; dz.N1cols = dz.N2cols = 0; dz.K = 32; dz.ntN = 1;
    dz.epi = 3; dz.bias = nullptr; dz.subp = nullptr;
    dz.out1 = dz.out2 = nullptr;

    // L2: pred (1024 blocks) || Wcomb2 (16) || Wcombv (8)
    GemmDesc d_pred = dz;
    d_pred.A = ctx_bf; d_pred.ldA = CTXV;
    d_pred.W1 = d_pred.W2 = Wpred_bf; d_pred.ldW = CTXV;
    d_pred.K = CTXV; d_pred.ntN = 16; d_pred.N1cols = DIMV; d_pred.epi = 0;
    d_pred.bias = bpred; d_pred.out1 = pred_bf;

    GemmDesc d_c2 = dz;
    d_c2.A = Wpv2_bf; d_c2.ldA = DIMV;
    d_c2.W1 = d_c2.W2 = WpredT_bf; d_c2.ldW = DIMV;
    d_c2.K = DIMV; d_c2.ntN = 4; d_c2.N1cols = CTXV; d_c2.epi = 3;
    d_c2.out1 = Wcomb2;

    GemmDesc d_cv = d_c2;
    d_cv.A = Wvip_bf;
    d_cv.out1 = Wcombv;

    pe_gemm5<<<dim3(1048), dim3(256), 0, stream>>>(d_pred, d_c2, d_cv, 1024, 1040);

    // L3: 2+3 (384 blocks) || 4'+5' (384 blocks, over ctx via Wcomb)
    GemmDesc d_23 = dz;
    d_23.A = x_bf; d_23.ldA = DIMV;
    d_23.W1 = Wpv1_bf; d_23.W2 = Wsomin_bf; d_23.ldW = DIMV;
    d_23.K = DIMV; d_23.ntN = 6; d_23.NB1 = NPV;
    d_23.N1cols = NPV; d_23.N2cols = NSV; d_23.epi = 1;
    d_23.out1 = rpv1_bf; d_23.out2 = ssom_bf;

    GemmDesc d_45 = dz;
    d_45.A = ctx_bf; d_45.ldA = CTXV;
    d_45.W1 = Wcomb2; d_45.W2 = Wcombv; d_45.ldW = CTXV;
    d_45.K = CTXV; d_45.ntN = 6; d_45.NB1 = NPV;
    d_45.N1cols = NPV; d_45.N2cols = NSV; d_45.epi = 4;
    d_45.bias = biascomb; d_45.out1 = rpv2_bf; d_45.out2 = rvip_bf;

    pe_gemm5<<<dim3(768), dim3(256), 0, stream>>>(d_23, d_45, dz, 384, 768);

    // L4: rsom = relu(ssom - rvip @ Wvipsom^T)  (128 blocks)
    GemmDesc d_som = dz;
    d_som.A = rvip_bf; d_som.ldA = NSV;
    d_som.W1 = d_som.W2 = Wvipsom_bf; d_som.ldW = NSV;
    d_som.K = NSV; d_som.ntN = 2; d_som.N1cols = NSV; d_som.epi = 2;
    d_som.subp = ssom_bf; d_som.out1 = rsom_bf;

    pe_gemm5<<<dim3(128), dim3(256), 0, stream>>>(d_som, d_som, d_som, 128, 128);

    // L5: merged FILT (1024 blocks)
    pe_filt5<<<dim3(1024), dim3(256), 0, stream>>>(
        rpv2_bf, Wpepos_bf, rpv1_bf, rsom_bf, Wpeneg_bf, Wsomd_bf,
        x_bf, pred_bf, r_pos, r_neg, out_pos, out_neg);
}

// Round 8
// 306.111 us; speedup vs baseline: 1.3818x; 1.0248x over previous
//
#include <hip/hip_runtime.h>
#include <hip/hip_bf16.h>
#include <stdint.h>
#include <stddef.h>

#define DIMV 2048
#define CTXV 512
#define BV   8192
#define NPV  512
#define NSV  256

typedef __attribute__((ext_vector_type(8))) __bf16 bf16x8;
typedef __attribute__((ext_vector_type(4))) __bf16 bf16x4;
typedef __attribute__((ext_vector_type(4))) float f32x4;
typedef __attribute__((ext_vector_type(4))) int   i32x4;
typedef __attribute__((address_space(3))) const char* lds_cp;

__device__ __forceinline__ void gload_lds16(const void* g, void* l) {
    __builtin_amdgcn_global_load_lds(
        (const __attribute__((address_space(1))) unsigned int*)g,
        (__attribute__((address_space(3))) unsigned int*)l,
        16, 0, 0);
}

// Inline-asm LDS read: NO memory clobber -> compiler sees no dependency on
// global_load_lds-written LDS, so it cannot insert its own vmcnt(0) drain.
// Ordering is enforced manually: lgkmcnt(0) + sched_barrier(0) before MFMA
// (rule #18), and s_barrier + counted vmcnt for cross-wave safety.
__device__ __forceinline__ bf16x8 lds_read16(const char* p) {
    i32x4 r;
    asm volatile("ds_read_b128 %0, %1" : "=v"(r) : "v"((lds_cp)p));
    return __builtin_bit_cast(bf16x8, r);
}

#define WAIT_VM4  asm volatile("s_waitcnt vmcnt(4)" ::: "memory")
#define WAIT_VM0  asm volatile("s_waitcnt vmcnt(0)" ::: "memory")
#define WAIT_LGKM asm volatile("s_waitcnt lgkmcnt(0)" ::: "memory")
#define SBAR      __builtin_amdgcn_s_barrier()
#define SCHEDB    __builtin_amdgcn_sched_barrier(0)

// ---------------------------------------------------------------------------
// Batched fp32 -> bf16 convert (x, ctx, 9 weights)
// ---------------------------------------------------------------------------
struct CvtArgs {
    const float* src[11];
    __bf16*      dst[11];
};

__global__ __launch_bounds__(256) void cvt_all(CvtArgs a) {
    constexpr int NSEG = 11;
    constexpr unsigned cum[NSEG + 1] = {
        0u, 2097152u, 2621440u, 2752512u, 2883584u, 3014656u,
        3080192u, 3145728u, 3153920u, 3284992u, 3416064u, 3481600u};
    const unsigned total = cum[NSEG];
    for (unsigned c = blockIdx.x * blockDim.x + threadIdx.x; c < total;
         c += gridDim.x * blockDim.x) {
        const float* sp = a.src[0];
        __bf16*      dp = a.dst[0];
        unsigned     base = 0;
#pragma unroll
        for (int t = 1; t < NSEG; ++t) {
            const bool g = (c >= cum[t]);
            sp   = g ? a.src[t] : sp;
            dp   = g ? a.dst[t] : dp;
            base = g ? cum[t] : base;
        }
        const unsigned off = (c - base) * 8u;
        f32x4 v0 = *(const f32x4*)(sp + off);
        f32x4 v1 = *(const f32x4*)(sp + off + 4);
        bf16x8 o;
#pragma unroll
        for (int e = 0; e < 4; ++e) { o[e] = (__bf16)v0[e]; o[e + 4] = (__bf16)v1[e]; }
        *(bf16x8*)(dp + off) = o;
    }
}

// ---------------------------------------------------------------------------
// Transpose-convert Wpred (2048x512 f32) -> WpredT (512x2048 bf16)
// ---------------------------------------------------------------------------
__global__ __launch_bounds__(256)
void cvtT_wpred(const float* __restrict__ W, __bf16* __restrict__ WT) {
    __shared__ float t[64 * 65];
    const int bi  = blockIdx.x & 31;
    const int bj  = blockIdx.x >> 5;
    const int tid = threadIdx.x;
    const int tr  = tid >> 4;
    const int tc  = tid & 15;
#pragma unroll
    for (int rr = 0; rr < 4; ++rr) {
        const int r = tr + rr * 16;
        f32x4 v = *(const f32x4*)(W + (size_t)(bi * 64 + r) * 512 + bj * 64 + tc * 4);
#pragma unroll
        for (int e = 0; e < 4; ++e) t[(tc * 4 + e) * 65 + r] = v[e];
    }
    __syncthreads();
#pragma unroll
    for (int rr = 0; rr < 4; ++rr) {
        const int c = tr + rr * 16;
        bf16x4 o;
#pragma unroll
        for (int e = 0; e < 4; ++e) o[e] = (__bf16)t[c * 65 + tc * 4 + e];
        *(bf16x4*)(WT + (size_t)(bj * 64 + c) * 2048 + bi * 64 + tc * 4) = o;
    }
}

// ---------------------------------------------------------------------------
// biascomb[0:512) = Wpv2 @ b_pred ; biascomb[512:768) = Wvip @ b_pred
// ---------------------------------------------------------------------------
__global__ __launch_bounds__(512)
void bias_comb(const __bf16* __restrict__ Wpv2, const __bf16* __restrict__ Wvip,
               const float* __restrict__ b, float* __restrict__ out) {
    const int tid  = threadIdx.x;
    const int gw   = blockIdx.x * 8 + (tid >> 6);
    const int lane = tid & 63;
    const __bf16* row = (gw < 512) ? (Wpv2 + (size_t)gw * 2048)
                                   : (Wvip + (size_t)(gw - 512) * 2048);
    float acc = 0.f;
#pragma unroll
    for (int c = 0; c < 4; ++c) {
        const int j = lane * 32 + c * 8;
        bf16x8 w = *(const bf16x8*)(row + j);
        f32x4 b0 = *(const f32x4*)(b + j);
        f32x4 b1 = *(const f32x4*)(b + j + 4);
#pragma unroll
        for (int e = 0; e < 4; ++e) acc += (float)w[e] * b0[e];
#pragma unroll
        for (int e = 0; e < 4; ++e) acc += (float)w[e + 4] * b1[e];
    }
#pragma unroll
    for (int off = 32; off > 0; off >>= 1) acc += __shfl_down(acc, off);
    if (lane == 0) out[gw] = acc;
}

// ---------------------------------------------------------------------------
// 128x128 tile, BK=32, 4 waves (2x2 of 64x64), 256 thr, 16x16x32 MFMA.
// 3-BUFFER, ONE-BARRIER COUNTED PIPELINE (asm ds_read so hipcc cannot
// insert an auto vmcnt(0) drain):
//   prologue: STAGE(0,b0); STAGE(1,b1);
//   iter s:   vmcnt(4) [stage s landed; s+1 in flight]; s_barrier;
//             STAGE(s+2,(s+2)%3) [overwrites buf(s-1): all reads of it
//               completed before this barrier via each wave's lgkmcnt(0)];
//             asm ds_read frags(buf s%3); lgkmcnt(0); sched_barrier;
//             setprio(1); 16 MFMA; setprio(0);
// Staging: global_load_lds(16B); read-side XOR swizzle (chunk ^= (row>>1)&3)
// via pre-swizzled GLOBAL source (rounds 2-7, 0 conflicts measured).
// MFMA operands SWAPPED:
//   batch row = m0 + wr*64 + i*16 + (lane&15)
//   out col   = n0 + wc*64 + j*16 + (lane>>4)*4 + r     [harness-verified]
// ---------------------------------------------------------------------------
struct GemmDesc {
    const __bf16* A; int ldA;
    const __bf16* W1; const __bf16* W2; int ldW;
    int NB1;             // N-concat boundary (mult of 128; huge if none)
    int N1cols, N2cols;
    int K, ntN;
    int epi;             // 0 bias->bf16, 1 relu-region, 2 subr, 3 plain, 4 bias768+relu-region
    const float* bias;
    const __bf16* subp;
    void* out1; void* out2;
};

#define GEOM4                                                     \
    const int tid  = threadIdx.x;                                 \
    const int wave = tid >> 6;                                    \
    const int lane = tid & 63;                                    \
    const int lhi  = lane >> 4;                                   \
    const int llo  = lane & 15;                                   \
    const int wr   = wave >> 1;                                   \
    const int wc   = wave & 1;                                    \
    const int rins = lane >> 2;                                   \
    const int ch   = lane & 3;

#define LOAD_FRAGS_ASM(BUF, af, bfr)                                  \
    _Pragma("unroll")                                                 \
    for (int i = 0; i < 4; ++i) {                                     \
        const int r  = wr * 64 + i * 16 + llo;                        \
        const int pc = lhi ^ ((r >> 1) & 3);                          \
        af[i] = lds_read16(&ldsA[BUF][r * 64 + pc * 16]);             \
    }                                                                 \
    _Pragma("unroll")                                                 \
    for (int j = 0; j < 4; ++j) {                                     \
        const int r  = wc * 64 + j * 16 + llo;                        \
        const int pc = lhi ^ ((r >> 1) & 3);                          \
        bfr[j] = lds_read16(&ldsB[BUF][r * 64 + pc * 16]);            \
    }

#define MFMA16(af, bfr, acc)                                                          \
    __builtin_amdgcn_s_setprio(1);                                                    \
    _Pragma("unroll")                                                                 \
    for (int i = 0; i < 4; ++i)                                                       \
        _Pragma("unroll")                                                             \
        for (int j = 0; j < 4; ++j)                                                   \
            acc[i][j] = __builtin_amdgcn_mfma_f32_16x16x32_bf16(bfr[j], af[i], acc[i][j], 0, 0, 0); \
    __builtin_amdgcn_s_setprio(0);

__global__ __launch_bounds__(256, 3)
void pe_gemm5(GemmDesc dA_, GemmDesc dB_, GemmDesc dC_, int s1, int s2)
{
    __shared__ __align__(16) char ldsA[3][8192];
    __shared__ __align__(16) char ldsB[3][8192];

    const int nwg = gridDim.x;
    const int bid = blockIdx.x;
    int wg = (bid & 7) * (nwg >> 3) + (bid >> 3);   // XCD-bijective (nwg%8==0)
    GemmDesc d = dA_;
    if (wg >= s2)      { d = dC_; wg -= s2; }
    else if (wg >= s1) { d = dB_; wg -= s1; }

    const int bx = wg / d.ntN;          // A-panel-major
    const int by = wg - bx * d.ntN;
    const int m0 = bx * 128;
    const int n0 = by * 128;

    const bool reg2  = (n0 >= d.NB1);
    const __bf16* Wc = reg2 ? d.W2 : d.W1;
    const int n0r    = reg2 ? (n0 - d.NB1) : n0;

    GEOM4

    const f32x4 fzero = {0.f, 0.f, 0.f, 0.f};
    f32x4 acc[4][4];
#pragma unroll
    for (int i = 0; i < 4; ++i)
#pragma unroll
        for (int j = 0; j < 4; ++j) acc[i][j] = fzero;

    const int nsteps = d.K >> 5;

#define STAGE5(S, BUF)                                                        \
    {                                                                         \
        const int kb_ = (S) * 32;                                             \
        _Pragma("unroll")                                                     \
        for (int half = 0; half < 2; ++half) {                                \
            const int rt = wave * 32 + half * 16 + rins;                      \
            const int kc = ch ^ ((rt >> 1) & 3);                              \
            const int kk = kb_ + kc * 8;                                      \
            gload_lds16(d.A + (size_t)(m0 + rt) * d.ldA + kk,                 \
                        &ldsA[BUF][wave * 2048 + half * 1024]);               \
            gload_lds16(Wc + (size_t)(n0r + rt) * d.ldW + kk,                 \
                        &ldsB[BUF][wave * 2048 + half * 1024]);               \
        }                                                                     \
    }

    STAGE5(0, 0)
    if (nsteps > 1) STAGE5(1, 1)
    for (int s = 0; s < nsteps; ++s) {
        if (s + 1 < nsteps) { WAIT_VM4; } else { WAIT_VM0; }
        SBAR;
        if (s + 2 < nsteps) STAGE5(s + 2, (s + 2) % 3)
        bf16x8 af[4], bfr[4];
        LOAD_FRAGS_ASM(s % 3, af, bfr)
        WAIT_LGKM; SCHEDB;
        MFMA16(af, bfr, acc)
    }
#undef STAGE5

#pragma unroll
    for (int i = 0; i < 4; ++i) {
#pragma unroll
        for (int j = 0; j < 4; ++j) {
            const int rowg = m0 + wr * 64 + i * 16 + llo;
            const int colb = wc * 64 + j * 16 + lhi * 4;
            if (d.epi == 0) {            // BIAS -> bf16
                const size_t idx = (size_t)rowg * d.N1cols + (n0 + colb);
                f32x4 b4 = *(const f32x4*)(d.bias + n0 + colb);
                bf16x4 o;
#pragma unroll
                for (int r = 0; r < 4; ++r) o[r] = (__bf16)(acc[i][j][r] + b4[r]);
                *(bf16x4*)((__bf16*)d.out1 + idx) = o;
            } else if (d.epi == 1) {     // RELU -> bf16, N-region
                __bf16* op    = reg2 ? (__bf16*)d.out2 : (__bf16*)d.out1;
                const int ldo = reg2 ? d.N2cols : d.N1cols;
                const size_t idx = (size_t)rowg * ldo + (n0r + colb);
                bf16x4 o;
#pragma unroll
                for (int r = 0; r < 4; ++r) o[r] = (__bf16)fmaxf(acc[i][j][r], 0.f);
                *(bf16x4*)(op + idx) = o;
            } else if (d.epi == 2) {     // SUBR: relu(subp - acc) -> bf16
                const size_t idx = (size_t)rowg * d.N1cols + (n0 + colb);
                bf16x4 s4 = *(const bf16x4*)(d.subp + idx);
                bf16x4 o;
#pragma unroll
                for (int r = 0; r < 4; ++r)
                    o[r] = (__bf16)fmaxf((float)s4[r] - acc[i][j][r], 0.f);
                *(bf16x4*)((__bf16*)d.out1 + idx) = o;
            } else if (d.epi == 3) {     // plain -> bf16
                const size_t idx = (size_t)rowg * d.N1cols + (n0 + colb);
                bf16x4 o;
#pragma unroll
                for (int r = 0; r < 4; ++r) o[r] = (__bf16)acc[i][j][r];
                *(bf16x4*)((__bf16*)d.out1 + idx) = o;
            } else {                     // bias768 + RELU -> bf16, N-region
                __bf16* op    = reg2 ? (__bf16*)d.out2 : (__bf16*)d.out1;
                const int ldo = reg2 ? d.N2cols : d.N1cols;
                const size_t idx = (size_t)rowg * ldo + (n0r + colb);
                f32x4 b4 = *(const f32x4*)(d.bias + n0 + colb);
                bf16x4 o;
#pragma unroll
                for (int r = 0; r < 4; ++r)
                    o[r] = (__bf16)fmaxf(acc[i][j][r] + b4[r], 0.f);
                *(bf16x4*)(op + idx) = o;
            }
        }
    }
}

// ---------------------------------------------------------------------------
// Merged FILT (steps 7+8), 128x128 tiles, same one-barrier counted pipeline.
//   out_pos = 0.9*r_pos + 0.1*relu( (x-pred) - rpv2 @ Wpepos^T)
//   out_neg = 0.9*r_neg + 0.1*relu( (pred-x) - rpv1 @ Wpeneg^T - rsom @ Wsomd^T)
// NEG prologue stages issued BEFORE the POS epilogue (latency hides there);
// explicit SBAR before them (buf0/1 reuse after POS's last reads).
// ---------------------------------------------------------------------------
__global__ __launch_bounds__(256, 3)
void pe_filt5(const __bf16* __restrict__ rpv2, const __bf16* __restrict__ Wpepos,
              const __bf16* __restrict__ rpv1, const __bf16* __restrict__ rsom,
              const __bf16* __restrict__ Wpeneg, const __bf16* __restrict__ Wsomd,
              const __bf16* __restrict__ xbf, const __bf16* __restrict__ predb,
              const float* __restrict__ rpos, const float* __restrict__ rneg,
              float* __restrict__ outp, float* __restrict__ outn)
{
    __shared__ __align__(16) char ldsA[3][8192];
    __shared__ __align__(16) char ldsB[3][8192];

    const int nwg = gridDim.x;
    const int bid = blockIdx.x;
    const int wg  = (bid & 7) * (nwg >> 3) + (bid >> 3);
    const int bx  = wg >> 4;          // A-panel-major, 16 n-tiles
    const int by  = wg & 15;
    const int m0  = bx * 128;
    const int n0  = by * 128;

    GEOM4

#define STAGE_F(Asrc, ldAv, Wsrc, ldWv, KB, BUF)                              \
    {                                                                         \
        _Pragma("unroll")                                                     \
        for (int half = 0; half < 2; ++half) {                                \
            const int rt = wave * 32 + half * 16 + rins;                      \
            const int kc = ch ^ ((rt >> 1) & 3);                              \
            const int kk = (KB) + kc * 8;                                     \
            gload_lds16((Asrc) + (size_t)(m0 + rt) * (ldAv) + kk,             \
                        &ldsA[BUF][wave * 2048 + half * 1024]);               \
            gload_lds16((Wsrc) + (size_t)(n0 + rt) * (ldWv) + kk,             \
                        &ldsB[BUF][wave * 2048 + half * 1024]);               \
        }                                                                     \
    }
#define STAGE_NEG(S, BUF)                                                     \
    {                                                                         \
        if ((S) < 16) { STAGE_F(rpv1, NPV, Wpeneg, NPV, (S) * 32, BUF) }      \
        else          { STAGE_F(rsom, NSV, Wsomd, NSV, ((S) - 16) * 32, BUF) }\
    }

    const f32x4 fzero = {0.f, 0.f, 0.f, 0.f};
    f32x4 acc[4][4];
#pragma unroll
    for (int i = 0; i < 4; ++i)
#pragma unroll
        for (int j = 0; j < 4; ++j) acc[i][j] = fzero;

    // ---- POS K-loop (K=512, 16 steps) ----
    STAGE_F(rpv2, NPV, Wpepos, NPV, 0, 0)
    STAGE_F(rpv2, NPV, Wpepos, NPV, 32, 1)
    for (int s = 0; s < 16; ++s) {
        if (s + 1 < 16) { WAIT_VM4; } else { WAIT_VM0; }
        SBAR;
        if (s + 2 < 16) STAGE_F(rpv2, NPV, Wpepos, NPV, (s + 2) * 32, (s + 2) % 3)
        bf16x8 af[4], bfr[4];
        LOAD_FRAGS_ASM(s % 3, af, bfr)
        WAIT_LGKM; SCHEDB;
        MFMA16(af, bfr, acc)
    }
    // all waves' reads of buf0/1 are complete after this barrier
    SBAR;
    STAGE_NEG(0, 0)
    STAGE_NEG(1, 1)

    // ---- POS epilogue (streams hide the NEG prologue latency) ----
#pragma unroll
    for (int i = 0; i < 4; ++i) {
#pragma unroll
        for (int j = 0; j < 4; ++j) {
            const int rowg = m0 + wr * 64 + i * 16 + llo;
            const int colg = n0 + wc * 64 + j * 16 + lhi * 4;
            const size_t idx = (size_t)rowg * 2048 + colg;
            f32x4 rp  = *(const f32x4*)(rpos + idx);
            bf16x4 xb = *(const bf16x4*)(xbf + idx);
            bf16x4 pb = *(const bf16x4*)(predb + idx);
            f32x4 o;
#pragma unroll
            for (int r = 0; r < 4; ++r) {
                const float dd = (float)xb[r] - (float)pb[r];
                o[r] = 0.9f * rp[r] + 0.1f * fmaxf(dd - acc[i][j][r], 0.f);
            }
            *(f32x4*)(outp + idx) = o;
            acc[i][j] = fzero;
        }
    }

    // ---- NEG K-loop (K=768 = 512 rpv1/Wpeneg + 256 rsom/Wsomd, 24 steps) ----
    for (int s = 0; s < 24; ++s) {
        if (s + 1 < 24) { WAIT_VM4; } else { WAIT_VM0; }
        SBAR;
        if (s + 2 < 24) STAGE_NEG(s + 2, (s + 2) % 3)
        bf16x8 af[4], bfr[4];
        LOAD_FRAGS_ASM(s % 3, af, bfr)
        WAIT_LGKM; SCHEDB;
        MFMA16(af, bfr, acc)
    }

    // ---- NEG epilogue ----
#pragma unroll
    for (int i = 0; i < 4; ++i) {
#pragma unroll
        for (int j = 0; j < 4; ++j) {
            const int rowg = m0 + wr * 64 + i * 16 + llo;
            const int colg = n0 + wc * 64 + j * 16 + lhi * 4;
            const size_t idx = (size_t)rowg * 2048 + colg;
            f32x4 rn  = *(const f32x4*)(rneg + idx);
            bf16x4 xb = *(const bf16x4*)(xbf + idx);
            bf16x4 pb = *(const bf16x4*)(predb + idx);
            f32x4 o;
#pragma unroll
            for (int r = 0; r < 4; ++r) {
                const float dd = (float)pb[r] - (float)xb[r];
                o[r] = 0.9f * rn[r] + 0.1f * fmaxf(dd - acc[i][j][r], 0.f);
            }
            *(f32x4*)(outn + idx) = o;
        }
    }
#undef STAGE_NEG
#undef STAGE_F
}

extern "C" void kernel_launch(void* const* d_in, const int* in_sizes, int n_in,
                              void* d_out, int out_size, void* d_ws, size_t ws_size,
                              hipStream_t stream) {
    (void)in_sizes; (void)n_in; (void)out_size; (void)ws_size;

    const float* x       = (const float*)d_in[0];
    const float* ctx     = (const float*)d_in[1];
    const float* r_pos   = (const float*)d_in[2];
    const float* r_neg   = (const float*)d_in[3];
    const float* Wpred   = (const float*)d_in[4];
    const float* bpred   = (const float*)d_in[5];
    const float* Wpv1    = (const float*)d_in[6];
    const float* Wpv2    = (const float*)d_in[7];
    const float* Wvip    = (const float*)d_in[8];
    const float* Wsomin  = (const float*)d_in[9];
    const float* Wvipsom = (const float*)d_in[10];
    const float* Wpepos  = (const float*)d_in[11];
    const float* Wpeneg  = (const float*)d_in[12];
    const float* Wsomd   = (const float*)d_in[13];

    char* ws = (char*)d_ws;
    __bf16* x_bf      = (__bf16*)ws; ws += (size_t)BV * DIMV * 2;
    __bf16* ctx_bf    = (__bf16*)ws; ws += (size_t)BV * CTXV * 2;
    __bf16* pred_bf   = (__bf16*)ws; ws += (size_t)BV * DIMV * 2;
    __bf16* rpv1_bf   = (__bf16*)ws; ws += (size_t)BV * NPV * 2;
    __bf16* rpv2_bf   = (__bf16*)ws; ws += (size_t)BV * NPV * 2;
    __bf16* rvip_bf   = (__bf16*)ws; ws += (size_t)BV * NSV * 2;
    __bf16* ssom_bf   = (__bf16*)ws; ws += (size_t)BV * NSV * 2;
    __bf16* rsom_bf   = (__bf16*)ws; ws += (size_t)BV * NSV * 2;
    __bf16* Wpred_bf  = (__bf16*)ws; ws += (size_t)DIMV * CTXV * 2;
    __bf16* Wpv1_bf   = (__bf16*)ws; ws += (size_t)NPV * DIMV * 2;
    __bf16* Wpv2_bf   = (__bf16*)ws; ws += (size_t)NPV * DIMV * 2;
    __bf16* Wvip_bf   = (__bf16*)ws; ws += (size_t)NSV * DIMV * 2;
    __bf16* Wsomin_bf = (__bf16*)ws; ws += (size_t)NSV * DIMV * 2;
    __bf16* Wvipsom_bf= (__bf16*)ws; ws += (size_t)NSV * NSV * 2;
    __bf16* Wpepos_bf = (__bf16*)ws; ws += (size_t)DIMV * NPV * 2;
    __bf16* Wpeneg_bf = (__bf16*)ws; ws += (size_t)DIMV * NPV * 2;
    __bf16* Wsomd_bf  = (__bf16*)ws; ws += (size_t)DIMV * NSV * 2;
    __bf16* WpredT_bf = (__bf16*)ws; ws += (size_t)CTXV * DIMV * 2;
    __bf16* Wcomb2    = (__bf16*)ws; ws += (size_t)NPV * CTXV * 2;
    __bf16* Wcombv    = (__bf16*)ws; ws += (size_t)NSV * CTXV * 2;
    float*  biascomb  = (float*)ws;  ws += 768 * 4;

    float* out_pos = (float*)d_out;
    float* out_neg = out_pos + (size_t)BV * DIMV;

    CvtArgs ca;
    ca.src[0] = x;       ca.dst[0] = x_bf;
    ca.src[1] = ctx;     ca.dst[1] = ctx_bf;
    ca.src[2] = Wpred;   ca.dst[2] = Wpred_bf;
    ca.src[3] = Wpv1;    ca.dst[3] = Wpv1_bf;
    ca.src[4] = Wpv2;    ca.dst[4] = Wpv2_bf;
    ca.src[5] = Wvip;    ca.dst[5] = Wvip_bf;
    ca.src[6] = Wsomin;  ca.dst[6] = Wsomin_bf;
    ca.src[7] = Wvipsom; ca.dst[7] = Wvipsom_bf;
    ca.src[8] = Wpepos;  ca.dst[8] = Wpepos_bf;
    ca.src[9] = Wpeneg;  ca.dst[9] = Wpeneg_bf;
    ca.src[10] = Wsomd;  ca.dst[10] = Wsomd_bf;
    cvt_all<<<dim3(2048), dim3(256), 0, stream>>>(ca);
    cvtT_wpred<<<dim3(256), dim3(256), 0, stream>>>(Wpred, WpredT_bf);
    bias_comb<<<dim3(96), dim3(512), 0, stream>>>(Wpv2_bf, Wvip_bf, bpred, biascomb);

    const int BIG = 1 << 28;
    GemmDesc dz;
    dz.A = nullptr; dz.ldA = 0; dz.W1 = dz.W2 = nullptr; dz.ldW = 0;
    dz.NB1 = BIG; dz.N1cols = dz.N2cols = 0; dz.K = 32; dz.ntN = 1;
    dz.epi = 3; dz.bias = nullptr; dz.subp = nullptr;
    dz.out1 = dz.out2 = nullptr;

    // L2: pred (1024 blocks) || Wcomb2 (16) || Wcombv (8)
    GemmDesc d_pred = dz;
    d_pred.A = ctx_bf; d_pred.ldA = CTXV;
    d_pred.W1 = d_pred.W2 = Wpred_bf; d_pred.ldW = CTXV;
    d_pred.K = CTXV; d_pred.ntN = 16; d_pred.N1cols = DIMV; d_pred.epi = 0;
    d_pred.bias = bpred; d_pred.out1 = pred_bf;

    GemmDesc d_c2 = dz;
    d_c2.A = Wpv2_bf; d_c2.ldA = DIMV;
    d_c2.W1 = d_c2.W2 = WpredT_bf; d_c2.ldW = DIMV;
    d_c2.K = DIMV; d_c2.ntN = 4; d_c2.N1cols = CTXV; d_c2.epi = 3;
    d_c2.out1 = Wcomb2;

    GemmDesc d_cv = d_c2;
    d_cv.A = Wvip_bf;
    d_cv.out1 = Wcombv;

    pe_gemm5<<<dim3(1048), dim3(256), 0, stream>>>(d_pred, d_c2, d_cv, 1024, 1040);

    // L3: 2+3 (384 blocks) || 4'+5' (384 blocks, over ctx via Wcomb)
    GemmDesc d_23 = dz;
    d_23.A = x_bf; d_23.ldA = DIMV;
    d_23.W1 = Wpv1_bf; d_23.W2 = Wsomin_bf; d_23.ldW = DIMV;
    d_23.K = DIMV; d_23.ntN = 6; d_23.NB1 = NPV;
    d_23.N1cols = NPV; d_23.N2cols = NSV; d_23.epi = 1;
    d_23.out1 = rpv1_bf; d_23.out2 = ssom_bf;

    GemmDesc d_45 = dz;
    d_45.A = ctx_bf; d_45.ldA = CTXV;
    d_45.W1 = Wcomb2; d_45.W2 = Wcombv; d_45.ldW = CTXV;
    d_45.K = CTXV; d_45.ntN = 6; d_45.NB1 = NPV;
    d_45.N1cols = NPV; d_45.N2cols = NSV; d_45.epi = 4;
    d_45.bias = biascomb; d_45.out1 = rpv2_bf; d_45.out2 = rvip_bf;

    pe_gemm5<<<dim3(768), dim3(256), 0, stream>>>(d_23, d_45, dz, 384, 768);

    // L4: rsom = relu(ssom - rvip @ Wvipsom^T)  (128 blocks)
    GemmDesc d_som = dz;
    d_som.A = rvip_bf; d_som.ldA = NSV;
    d_som.W1 = d_som.W2 = Wvipsom_bf; d_som.ldW = NSV;
    d_som.K = NSV; d_som.ntN = 2; d_som.N1cols = NSV; d_som.epi = 2;
    d_som.subp = ssom_bf; d_som.out1 = rsom_bf;

    pe_gemm5<<<dim3(128), dim3(256), 0, stream>>>(d_som, d_som, d_som, 128, 128);

    // L5: merged FILT (1024 blocks)
    pe_filt5<<<dim3(1024), dim3(256), 0, stream>>>(
        rpv2_bf, Wpepos_bf, rpv1_bf, rsom_bf, Wpeneg_bf, Wsomd_bf,
        x_bf, pred_bf, r_pos, r_neg, out_pos, out_neg);
}

// Round 9
// 289.968 us; speedup vs baseline: 1.4587x; 1.0557x over previous
//
#include <hip/hip_runtime.h>
#include <hip/hip_bf16.h>
#include <stdint.h>
#include <stddef.h>

#define DIMV 2048
#define CTXV 512
#define BV   8192
#define NPV  512
#define NSV  256

typedef __attribute__((ext_vector_type(8))) __bf16 bf16x8;
typedef __attribute__((ext_vector_type(4))) __bf16 bf16x4;
typedef __attribute__((ext_vector_type(4))) float f32x4;

// ---------------------------------------------------------------------------
// FM (fragment-major) layout for a [R][K] bf16 matrix, nks = K/32:
//   16B-chunk index q(r, kc) = ((r>>4)*nks + (kc>>2))*64 + (kc&3)*16 + (r&15)
//   (kc = k>>3); byte addr = q*16 + (k&7)*2.
// Wave frag (rows base_r..base_r+15, K-step s, chunk lhi=lane>>4, row llo):
//   byte = ((base_r>>4)*nks + s)*1024 + lane*16   -> perfectly coalesced 1KB.
// This removes LDS staging and ALL barriers from every GEMM.
// ---------------------------------------------------------------------------
__device__ __forceinline__ size_t fmq(int base_r, int Cb, int lhi, int llo, int nks) {
    const int kc = (Cb >> 3) + (lhi >> 1);
    return ((size_t)(base_r >> 4) * nks + (kc >> 2)) * 64 + (size_t)(kc & 3) * 16 + llo;
}

// ---------------------------------------------------------------------------
// fp32 -> FM bf16 converter for 12 matrices (ctx, x, 10 weight views).
// Thread <-> one 16B output chunk; writes fully coalesced.
// ---------------------------------------------------------------------------
struct FmJob { const float* src; char* dst; int lognks; int ld; int trans; };
struct FmArgs { FmJob j[12]; unsigned cum[13]; };

__global__ __launch_bounds__(256) void cvt_fm(FmArgs a) {
    const unsigned total = a.cum[12];
    for (unsigned c = blockIdx.x * blockDim.x + threadIdx.x; c < total;
         c += gridDim.x * blockDim.x) {
        int seg = 0;
#pragma unroll
        for (int t = 1; t < 12; ++t) seg = (c >= a.cum[t]) ? t : seg;
        const FmJob jb = a.j[seg];
        const unsigned q = c - a.cum[seg];
        const int llo = q & 15, ch = (q >> 4) & 3;
        const unsigned blk = q >> 6;
        const unsigned s = blk & ((1u << jb.lognks) - 1u);
        const unsigned g = blk >> jb.lognks;
        const int row = g * 16 + llo;
        const int k0  = s * 32 + ch * 8;
        bf16x8 o;
        if (!jb.trans) {
            f32x4 v0 = *(const f32x4*)(jb.src + (size_t)row * jb.ld + k0);
            f32x4 v1 = *(const f32x4*)(jb.src + (size_t)row * jb.ld + k0 + 4);
#pragma unroll
            for (int e = 0; e < 4; ++e) { o[e] = (__bf16)v0[e]; o[e + 4] = (__bf16)v1[e]; }
        } else {
#pragma unroll
            for (int e = 0; e < 8; ++e)
                o[e] = (__bf16)jb.src[(size_t)(k0 + e) * jb.ld + row];
        }
        *(bf16x8*)(jb.dst + (size_t)q * 16) = o;
    }
}

// ---------------------------------------------------------------------------
// biascomb[0:512) = Wpv2 @ b_pred ; biascomb[512:768) = Wvip @ b_pred (f32 in)
// ---------------------------------------------------------------------------
__global__ __launch_bounds__(512)
void bias_comb(const float* __restrict__ Wpv2, const float* __restrict__ Wvip,
               const float* __restrict__ b, float* __restrict__ out) {
    const int tid  = threadIdx.x;
    const int gw   = blockIdx.x * 8 + (tid >> 6);
    const int lane = tid & 63;
    const float* row = (gw < 512) ? (Wpv2 + (size_t)gw * 2048)
                                  : (Wvip + (size_t)(gw - 512) * 2048);
    float acc = 0.f;
#pragma unroll
    for (int c = 0; c < 8; ++c) {
        const int j = lane * 32 + c * 4;
        f32x4 w  = *(const f32x4*)(row + j);
        f32x4 bb = *(const f32x4*)(b + j);
#pragma unroll
        for (int e = 0; e < 4; ++e) acc += w[e] * bb[e];
    }
#pragma unroll
    for (int off = 32; off > 0; off >>= 1) acc += __shfl_down(acc, off);
    if (lane == 0) out[gw] = acc;
}

// ---------------------------------------------------------------------------
// LDS-FREE FM GEMM: 128x128 block, 4 free-running waves (2x2 of 64x64),
// BK=32, 16x16x32 MFMA, register double-buffer (2 K-steps in flight),
// zero barriers. MFMA operands SWAPPED:
//   batch row = m0 + wr*64 + i*16 + (lane&15)
//   out col   = n0 + wc*64 + j*16 + (lane>>4)*4 + r     [harness-verified]
// ---------------------------------------------------------------------------
#define GEOM4                                                     \
    const int tid  = threadIdx.x;                                 \
    const int wave = tid >> 6;                                    \
    const int lane = tid & 63;                                    \
    const int lhi  = lane >> 4;                                   \
    const int llo  = lane & 15;                                   \
    const int wr   = wave >> 1;                                   \
    const int wc   = wave & 1;

#define SETPA(Abase, nksA_)                                                   \
    _Pragma("unroll")                                                         \
    for (int i_ = 0; i_ < 4; ++i_) {                                          \
        const int g_ = (m0 + wr * 64 + i_ * 16) >> 4;                         \
        pa[i_] = (const char*)(Abase) + ((size_t)g_ * (nksA_)) * 1024 + lane * 16; \
    }
#define SETPW(Wbase, nksW_, nbase)                                            \
    _Pragma("unroll")                                                         \
    for (int j_ = 0; j_ < 4; ++j_) {                                          \
        const int g_ = ((nbase) + wc * 64 + j_ * 16) >> 4;                    \
        pw[j_] = (const char*)(Wbase) + ((size_t)g_ * (nksW_)) * 1024 + lane * 16; \
    }
#define LD8(AF, BF, OFS)                                                      \
    _Pragma("unroll")                                                         \
    for (int i_ = 0; i_ < 4; ++i_) AF[i_] = *(const bf16x8*)(pa[i_] + (OFS)); \
    _Pragma("unroll")                                                         \
    for (int j_ = 0; j_ < 4; ++j_) BF[j_] = *(const bf16x8*)(pw[j_] + (OFS));
#define ADV2                                                                  \
    _Pragma("unroll")                                                         \
    for (int i_ = 0; i_ < 4; ++i_) pa[i_] += 2048;                            \
    _Pragma("unroll")                                                         \
    for (int j_ = 0; j_ < 4; ++j_) pw[j_] += 2048;
#define MFMA16(af, bfr, acc)                                                  \
    __builtin_amdgcn_s_setprio(1);                                            \
    _Pragma("unroll")                                                         \
    for (int i = 0; i < 4; ++i)                                               \
        _Pragma("unroll")                                                     \
        for (int j = 0; j < 4; ++j)                                           \
            acc[i][j] = __builtin_amdgcn_mfma_f32_16x16x32_bf16(bfr[j], af[i], acc[i][j], 0, 0, 0); \
    __builtin_amdgcn_s_setprio(0);

struct GemmDesc {
    const char* A; int nksA;
    const char* W1; const char* W2; int nksW;
    int NB1, ntN, nsteps, epi;   // epi: 0 bias, 1 relu-region, 2 subr, 3 plain, 4 bias768+relu-region
    const float* bias;
    const char* subp; int nksSub;
    char* out1; int nksO1; char* out2; int nksO2;
};

__global__ __launch_bounds__(256)
void pe_gemm6(GemmDesc dA_, GemmDesc dB_, GemmDesc dC_, int s1, int s2)
{
    const int nwg = gridDim.x;
    const int bid = blockIdx.x;
    int wg = (bid & 7) * (nwg >> 3) + (bid >> 3);   // XCD-bijective (nwg%8==0)
    GemmDesc d = dA_;
    if (wg >= s2)      { d = dC_; wg -= s2; }
    else if (wg >= s1) { d = dB_; wg -= s1; }

    const int bx = wg / d.ntN;           // A-panel-major
    const int by = wg - bx * d.ntN;
    const int m0 = bx * 128;
    const int n0 = by * 128;

    const bool reg2  = (d.W2 != nullptr) && (n0 >= d.NB1);
    const char* Wc   = reg2 ? d.W2 : d.W1;
    const int n0r    = reg2 ? (n0 - d.NB1) : n0;

    GEOM4

    const f32x4 fzero = {0.f, 0.f, 0.f, 0.f};
    f32x4 acc[4][4];
#pragma unroll
    for (int i = 0; i < 4; ++i)
#pragma unroll
        for (int j = 0; j < 4; ++j) acc[i][j] = fzero;

    const char* pa[4]; const char* pw[4];
    SETPA(d.A, d.nksA)
    SETPW(Wc, d.nksW, n0r)

    bf16x8 A0[4], B0[4], A1[4], B1[4];
    LD8(A0, B0, 0)
    const int half = d.nsteps >> 1;      // nsteps always even here
    for (int it = 0; it < half; ++it) {
        LD8(A1, B1, 1024)
        MFMA16(A0, B0, acc)
        ADV2
        if (it + 1 < half) { LD8(A0, B0, 0) }
        MFMA16(A1, B1, acc)
    }

#pragma unroll
    for (int i = 0; i < 4; ++i) {
#pragma unroll
        for (int j = 0; j < 4; ++j) {
            const int base_r = m0 + wr * 64 + i * 16;
            const int CbL    = (reg2 ? n0r : n0) + wc * 64 + j * 16;  // region-local
            if (d.epi == 0) {            // bias -> FM bf16
                const int colg = n0 + wc * 64 + j * 16 + lhi * 4;
                f32x4 b4 = *(const f32x4*)(d.bias + colg);
                bf16x4 o;
#pragma unroll
                for (int r = 0; r < 4; ++r) o[r] = (__bf16)(acc[i][j][r] + b4[r]);
                *(bf16x4*)(d.out1 + fmq(base_r, CbL, lhi, llo, d.nksO1) * 16 + (lhi & 1) * 8) = o;
            } else if (d.epi == 1) {     // relu -> FM bf16, N-region
                char* op     = reg2 ? d.out2 : d.out1;
                const int nk = reg2 ? d.nksO2 : d.nksO1;
                bf16x4 o;
#pragma unroll
                for (int r = 0; r < 4; ++r) o[r] = (__bf16)fmaxf(acc[i][j][r], 0.f);
                *(bf16x4*)(op + fmq(base_r, CbL, lhi, llo, nk) * 16 + (lhi & 1) * 8) = o;
            } else if (d.epi == 2) {     // relu(subp - acc) -> FM bf16
                bf16x4 s4 = *(const bf16x4*)(d.subp + fmq(base_r, CbL, lhi, llo, d.nksSub) * 16 + (lhi & 1) * 8);
                bf16x4 o;
#pragma unroll
                for (int r = 0; r < 4; ++r)
                    o[r] = (__bf16)fmaxf((float)s4[r] - acc[i][j][r], 0.f);
                *(bf16x4*)(d.out1 + fmq(base_r, CbL, lhi, llo, d.nksO1) * 16 + (lhi & 1) * 8) = o;
            } else if (d.epi == 3) {     // plain -> FM bf16 (Wcomb)
                bf16x4 o;
#pragma unroll
                for (int r = 0; r < 4; ++r) o[r] = (__bf16)acc[i][j][r];
                *(bf16x4*)(d.out1 + fmq(base_r, CbL, lhi, llo, d.nksO1) * 16 + (lhi & 1) * 8) = o;
            } else {                     // bias768 + relu -> FM bf16, N-region
                const int colg = n0 + wc * 64 + j * 16 + lhi * 4;
                f32x4 b4 = *(const f32x4*)(d.bias + colg);
                char* op     = reg2 ? d.out2 : d.out1;
                const int nk = reg2 ? d.nksO2 : d.nksO1;
                bf16x4 o;
#pragma unroll
                for (int r = 0; r < 4; ++r)
                    o[r] = (__bf16)fmaxf(acc[i][j][r] + b4[r], 0.f);
                *(bf16x4*)(op + fmq(base_r, CbL, lhi, llo, nk) * 16 + (lhi & 1) * 8) = o;
            }
        }
    }
}

// ---------------------------------------------------------------------------
// Merged FILT (steps 7+8), LDS-free FM, barrier-free.
//   out_pos = 0.9*r_pos + 0.1*relu( (x-pred) - rpv2 @ Wpepos^T)
//   out_neg = 0.9*r_neg + 0.1*relu( (pred-x) - rpv1 @ Wpeneg^T - rsom @ Wsomd^T)
// x/pred read via FM bijection (nks=64); r_old / outputs natural f32.
// First NEG loads issued before the POS epilogue (latency hides there).
// ---------------------------------------------------------------------------
__global__ __launch_bounds__(256)
void pe_filt6(const char* __restrict__ rpv2f, const char* __restrict__ Wposf,
              const char* __restrict__ rpv1f, const char* __restrict__ rsomf,
              const char* __restrict__ Wneg1f, const char* __restrict__ Wneg2f,
              const char* __restrict__ xfm, const char* __restrict__ predfm,
              const float* __restrict__ rpos, const float* __restrict__ rneg,
              float* __restrict__ outp, float* __restrict__ outn)
{
    const int nwg = gridDim.x;
    const int bid = blockIdx.x;
    const int wg  = (bid & 7) * (nwg >> 3) + (bid >> 3);
    const int bx  = wg >> 4;          // panel-major, 16 n-tiles
    const int by  = wg & 15;
    const int m0  = bx * 128;
    const int n0  = by * 128;

    GEOM4

    const f32x4 fzero = {0.f, 0.f, 0.f, 0.f};
    f32x4 acc[4][4];
#pragma unroll
    for (int i = 0; i < 4; ++i)
#pragma unroll
        for (int j = 0; j < 4; ++j) acc[i][j] = fzero;

    const char* pa[4]; const char* pw[4];
    bf16x8 A0[4], B0[4], A1[4], B1[4];

    // ---- POS: K=512, nks=16, 16 steps = 8 iters ----
    SETPA(rpv2f, 16)
    SETPW(Wposf, 16, n0)
    LD8(A0, B0, 0)
    for (int it = 0; it < 8; ++it) {
        LD8(A1, B1, 1024)
        MFMA16(A0, B0, acc)
        ADV2
        if (it + 1 < 8) { LD8(A0, B0, 0) }
        MFMA16(A1, B1, acc)
    }
    // issue first NEG loads now; they land under the POS epilogue
    SETPA(rpv1f, 16)
    SETPW(Wneg1f, 16, n0)
    LD8(A0, B0, 0)

    // ---- POS epilogue ----
#pragma unroll
    for (int i = 0; i < 4; ++i) {
#pragma unroll
        for (int j = 0; j < 4; ++j) {
            const int base_r = m0 + wr * 64 + i * 16;
            const int Cb     = n0 + wc * 64 + j * 16;
            const int rowg   = base_r + llo;
            const int colg   = Cb + lhi * 4;
            const size_t idx = (size_t)rowg * 2048 + colg;
            const size_t qx  = fmq(base_r, Cb, lhi, llo, 64) * 16 + (lhi & 1) * 8;
            f32x4 rp  = *(const f32x4*)(rpos + idx);
            bf16x4 xb = *(const bf16x4*)(xfm + qx);
            bf16x4 pb = *(const bf16x4*)(predfm + qx);
            f32x4 o;
#pragma unroll
            for (int r = 0; r < 4; ++r) {
                const float dd = (float)xb[r] - (float)pb[r];
                o[r] = 0.9f * rp[r] + 0.1f * fmaxf(dd - acc[i][j][r], 0.f);
            }
            *(f32x4*)(outp + idx) = o;
            acc[i][j] = fzero;
        }
    }

    // ---- NEG part 1: rpv1/Wpeneg, 16 steps (A0/B0 step0 already in flight) ----
    for (int it = 0; it < 8; ++it) {
        LD8(A1, B1, 1024)
        MFMA16(A0, B0, acc)
        ADV2
        if (it + 1 < 8) { LD8(A0, B0, 0) }
        MFMA16(A1, B1, acc)
    }
    // ---- NEG part 2: rsom/Wsomd, nks=8, 8 steps = 4 iters ----
    SETPA(rsomf, 8)
    SETPW(Wneg2f, 8, n0)
    LD8(A0, B0, 0)
    for (int it = 0; it < 4; ++it) {
        LD8(A1, B1, 1024)
        MFMA16(A0, B0, acc)
        ADV2
        if (it + 1 < 4) { LD8(A0, B0, 0) }
        MFMA16(A1, B1, acc)
    }

    // ---- NEG epilogue ----
#pragma unroll
    for (int i = 0; i < 4; ++i) {
#pragma unroll
        for (int j = 0; j < 4; ++j) {
            const int base_r = m0 + wr * 64 + i * 16;
            const int Cb     = n0 + wc * 64 + j * 16;
            const int rowg   = base_r + llo;
            const int colg   = Cb + lhi * 4;
            const size_t idx = (size_t)rowg * 2048 + colg;
            const size_t qx  = fmq(base_r, Cb, lhi, llo, 64) * 16 + (lhi & 1) * 8;
            f32x4 rn  = *(const f32x4*)(rneg + idx);
            bf16x4 xb = *(const bf16x4*)(xfm + qx);
            bf16x4 pb = *(const bf16x4*)(predfm + qx);
            f32x4 o;
#pragma unroll
            for (int r = 0; r < 4; ++r) {
                const float dd = (float)pb[r] - (float)xb[r];
                o[r] = 0.9f * rn[r] + 0.1f * fmaxf(dd - acc[i][j][r], 0.f);
            }
            *(f32x4*)(outn + idx) = o;
        }
    }
}

extern "C" void kernel_launch(void* const* d_in, const int* in_sizes, int n_in,
                              void* d_out, int out_size, void* d_ws, size_t ws_size,
                              hipStream_t stream) {
    (void)in_sizes; (void)n_in; (void)out_size; (void)ws_size;

    const float* x       = (const float*)d_in[0];
    const float* ctx     = (const float*)d_in[1];
    const float* r_pos   = (const float*)d_in[2];
    const float* r_neg   = (const float*)d_in[3];
    const float* Wpred   = (const float*)d_in[4];
    const float* bpred   = (const float*)d_in[5];
    const float* Wpv1    = (const float*)d_in[6];
    const float* Wpv2    = (const float*)d_in[7];
    const float* Wvip    = (const float*)d_in[8];
    const float* Wsomin  = (const float*)d_in[9];
    const float* Wvipsom = (const float*)d_in[10];
    const float* Wpepos  = (const float*)d_in[11];
    const float* Wpeneg  = (const float*)d_in[12];
    const float* Wsomd   = (const float*)d_in[13];

    char* ws = (char*)d_ws;
    char* ctx_fm     = ws; ws += (size_t)BV * CTXV * 2;
    char* x_fm       = ws; ws += (size_t)BV * DIMV * 2;
    char* pred_fm    = ws; ws += (size_t)BV * DIMV * 2;
    char* rpv1_fm    = ws; ws += (size_t)BV * NPV * 2;
    char* rpv2_fm    = ws; ws += (size_t)BV * NPV * 2;
    char* rvip_fm    = ws; ws += (size_t)BV * NSV * 2;
    char* ssom_fm    = ws; ws += (size_t)BV * NSV * 2;
    char* rsom_fm    = ws; ws += (size_t)BV * NSV * 2;
    char* Wpred_fm   = ws; ws += (size_t)DIMV * CTXV * 2;
    char* WpredT_fm  = ws; ws += (size_t)CTXV * DIMV * 2;
    char* Wpv1_fm    = ws; ws += (size_t)NPV * DIMV * 2;
    char* Wpv2_fm    = ws; ws += (size_t)NPV * DIMV * 2;
    char* Wvip_fm    = ws; ws += (size_t)NSV * DIMV * 2;
    char* Wsomin_fm  = ws; ws += (size_t)NSV * DIMV * 2;
    char* Wvipsom_fm = ws; ws += (size_t)NSV * NSV * 2;
    char* Wpepos_fm  = ws; ws += (size_t)DIMV * NPV * 2;
    char* Wpeneg_fm  = ws; ws += (size_t)DIMV * NPV * 2;
    char* Wsomd_fm   = ws; ws += (size_t)DIMV * NSV * 2;
    char* Wcomb2_fm  = ws; ws += (size_t)NPV * CTXV * 2;
    char* Wcombv_fm  = ws; ws += (size_t)NSV * CTXV * 2;
    float* biascomb  = (float*)ws; ws += 768 * 4;

    float* out_pos = (float*)d_out;
    float* out_neg = out_pos + (size_t)BV * DIMV;

    // ---- FM conversions (12 jobs) ----
    FmArgs fa;
    auto setj = [&](int t, const float* s, char* dst, int lognks, int ld, int trans) {
        fa.j[t].src = s; fa.j[t].dst = dst; fa.j[t].lognks = lognks;
        fa.j[t].ld = ld; fa.j[t].trans = trans;
    };
    setj(0,  ctx,     ctx_fm,     4, 512,  0);
    setj(1,  x,       x_fm,       6, 2048, 0);
    setj(2,  Wpred,   Wpred_fm,   4, 512,  0);
    setj(3,  Wpred,   WpredT_fm,  6, 512,  1);   // WpredT[r][k] = Wpred[k][r]
    setj(4,  Wpv1,    Wpv1_fm,    6, 2048, 0);
    setj(5,  Wpv2,    Wpv2_fm,    6, 2048, 0);
    setj(6,  Wvip,    Wvip_fm,    6, 2048, 0);
    setj(7,  Wsomin,  Wsomin_fm,  6, 2048, 0);
    setj(8,  Wvipsom, Wvipsom_fm, 3, 256,  0);
    setj(9,  Wpepos,  Wpepos_fm,  4, 512,  0);
    setj(10, Wpeneg,  Wpeneg_fm,  4, 512,  0);
    setj(11, Wsomd,   Wsomd_fm,   3, 256,  0);
    const unsigned cum[13] = {0u, 524288u, 2621440u, 2752512u, 2883584u,
                              3014656u, 3145728u, 3211264u, 3276800u,
                              3284992u, 3416064u, 3547136u, 3612672u};
    for (int t = 0; t < 13; ++t) fa.cum[t] = cum[t];
    cvt_fm<<<dim3(2048), dim3(256), 0, stream>>>(fa);
    bias_comb<<<dim3(96), dim3(512), 0, stream>>>(Wpv2, Wvip, bpred, biascomb);

    const int BIG = 1 << 28;
    GemmDesc dz;
    dz.A = nullptr; dz.nksA = 1; dz.W1 = dz.W2 = nullptr; dz.nksW = 1;
    dz.NB1 = BIG; dz.ntN = 1; dz.nsteps = 2; dz.epi = 3;
    dz.bias = nullptr; dz.subp = nullptr; dz.nksSub = 1;
    dz.out1 = nullptr; dz.nksO1 = 1; dz.out2 = nullptr; dz.nksO2 = 1;

    // L2: pred (1024 blocks) || Wcomb2 (16) || Wcombv (8)
    GemmDesc d_pred = dz;
    d_pred.A = ctx_fm; d_pred.nksA = 16;
    d_pred.W1 = Wpred_fm; d_pred.nksW = 16;
    d_pred.ntN = 16; d_pred.nsteps = 16; d_pred.epi = 0;
    d_pred.bias = bpred; d_pred.out1 = pred_fm; d_pred.nksO1 = 64;

    GemmDesc d_c2 = dz;
    d_c2.A = Wpv2_fm; d_c2.nksA = 64;
    d_c2.W1 = WpredT_fm; d_c2.nksW = 64;
    d_c2.ntN = 4; d_c2.nsteps = 64; d_c2.epi = 3;
    d_c2.out1 = Wcomb2_fm; d_c2.nksO1 = 16;

    GemmDesc d_cv = d_c2;
    d_cv.A = Wvip_fm;
    d_cv.out1 = Wcombv_fm; d_cv.nksO1 = 16;

    pe_gemm6<<<dim3(1048), dim3(256), 0, stream>>>(d_pred, d_c2, d_cv, 1024, 1040);

    // L3: 2+3 (384) || 4'+5' (384)
    GemmDesc d_23 = dz;
    d_23.A = x_fm; d_23.nksA = 64;
    d_23.W1 = Wpv1_fm; d_23.W2 = Wsomin_fm; d_23.nksW = 64;
    d_23.NB1 = NPV; d_23.ntN = 6; d_23.nsteps = 64; d_23.epi = 1;
    d_23.out1 = rpv1_fm; d_23.nksO1 = 16;
    d_23.out2 = ssom_fm; d_23.nksO2 = 8;

    GemmDesc d_45 = dz;
    d_45.A = ctx_fm; d_45.nksA = 16;
    d_45.W1 = Wcomb2_fm; d_45.W2 = Wcombv_fm; d_45.nksW = 16;
    d_45.NB1 = NPV; d_45.ntN = 6; d_45.nsteps = 16; d_45.epi = 4;
    d_45.bias = biascomb;
    d_45.out1 = rpv2_fm; d_45.nksO1 = 16;
    d_45.out2 = rvip_fm; d_45.nksO2 = 8;

    pe_gemm6<<<dim3(768), dim3(256), 0, stream>>>(d_23, d_45, dz, 384, 768);

    // L4: rsom = relu(ssom - rvip @ Wvipsom^T)  (128 blocks)
    GemmDesc d_som = dz;
    d_som.A = rvip_fm; d_som.nksA = 8;
    d_som.W1 = Wvipsom_fm; d_som.nksW = 8;
    d_som.ntN = 2; d_som.nsteps = 8; d_som.epi = 2;
    d_som.subp = ssom_fm; d_som.nksSub = 8;
    d_som.out1 = rsom_fm; d_som.nksO1 = 8;

    pe_gemm6<<<dim3(128), dim3(256), 0, stream>>>(d_som, d_som, d_som, 128, 128);

    // L5: merged FILT (1024 blocks)
    pe_filt6<<<dim3(1024), dim3(256), 0, stream>>>(
        rpv2_fm, Wpepos_fm, rpv1_fm, rsom_fm, Wpeneg_fm, Wsomd_fm,
        x_fm, pred_fm, r_pos, r_neg, out_pos, out_neg);
}